// Round 2
// baseline (921.397 us; speedup 1.0000x reference)
//
#include <hip/hip_runtime.h>
#include <hip/hip_bf16.h>
#include <math.h>

#define NEG_SLOPE 0.2f

// ---------------- GEMM: H = X @ W  (X:[N,128], W:[128,128], f64 accum) ------
// 256 threads = 8 rows x 32 col-groups; each thread does 4 output cols.
__global__ __launch_bounds__(256) void gemm128_kernel(
    const float* __restrict__ X, const float* __restrict__ W,
    float* __restrict__ Hout, int N)
{
    int n  = blockIdx.x * 8 + (threadIdx.x >> 5);
    int j0 = (threadIdx.x & 31) * 4;
    if (n >= N) return;
    const float* xrow = X + (size_t)n * 128;
    double a0 = 0, a1 = 0, a2 = 0, a3 = 0;
    #pragma unroll 4
    for (int k = 0; k < 128; ++k) {
        double xv = (double)xrow[k];
        float4 w = *(const float4*)(W + k * 128 + j0);
        a0 += xv * (double)w.x; a1 += xv * (double)w.y;
        a2 += xv * (double)w.z; a3 += xv * (double)w.w;
    }
    float4 o = make_float4((float)a0, (float)a1, (float)a2, (float)a3);
    *(float4*)(Hout + (size_t)n * 128 + j0) = o;
}

// ---------------- alpha dots: as[n,h], ad[n,h] ------------------------------
__global__ __launch_bounds__(256) void alpha_kernel(
    const float* __restrict__ H, const float* __restrict__ a_src,
    const float* __restrict__ a_dst, float* __restrict__ as_out,
    float* __restrict__ ad_out, int N)
{
    int n = blockIdx.x * 2 + (threadIdx.x >> 7);
    if (n >= N) return;
    int i = threadIdx.x & 127;
    float hv = H[(size_t)n * 128 + i];
    double ps = (double)hv * (double)a_src[i];
    double pd = (double)hv * (double)a_dst[i];
    #pragma unroll
    for (int off = 16; off; off >>= 1) {
        ps += __shfl_xor(ps, off, 64);
        pd += __shfl_xor(pd, off, 64);
    }
    if ((i & 31) == 0) {
        as_out[n * 4 + (i >> 5)] = (float)ps;
        ad_out[n * 4 + (i >> 5)] = (float)pd;
    }
}

// ---------------- CSR build helpers -----------------------------------------
__global__ __launch_bounds__(256) void zero_int_kernel(int* __restrict__ p, int n)
{
    int i = blockIdx.x * 256 + threadIdx.x;
    if (i < n) p[i] = 0;
}

__global__ __launch_bounds__(256) void copy_int_kernel(
    const int* __restrict__ src, int* __restrict__ dst, int n)
{
    int i = blockIdx.x * 256 + threadIdx.x;
    if (i < n) dst[i] = src[i];
}

__global__ __launch_bounds__(256) void count_kernel(
    const int* __restrict__ edst, int E, int Et, int* __restrict__ cnt)
{
    int e = blockIdx.x * 256 + threadIdx.x;
    if (e >= Et) return;
    int d = (e < E) ? edst[e] : (e - E);
    atomicAdd(&cnt[d], 1);
}

// exclusive scan within each 256-block; bsum[b] = block total
__global__ __launch_bounds__(256) void scan_block_kernel(
    const int* __restrict__ in, int* __restrict__ out,
    int* __restrict__ bsum, int n)
{
    __shared__ int sh[256];
    int i = blockIdx.x * 256 + threadIdx.x;
    int v = (i < n) ? in[i] : 0;
    sh[threadIdx.x] = v;
    __syncthreads();
    #pragma unroll
    for (int off = 1; off < 256; off <<= 1) {
        int t = 0;
        if (threadIdx.x >= off) t = sh[threadIdx.x - off];
        __syncthreads();
        if (threadIdx.x >= off) sh[threadIdx.x] += t;
        __syncthreads();
    }
    if (i < n) out[i] = sh[threadIdx.x] - v;        // exclusive
    if (threadIdx.x == 255) bsum[blockIdx.x] = sh[255];
}

__global__ __launch_bounds__(256) void scan_add_kernel(
    int* __restrict__ offs, const int* __restrict__ bsum, int n)
{
    int i = blockIdx.x * 256 + threadIdx.x;
    if (i < n) offs[i] += bsum[blockIdx.x];
}

__global__ __launch_bounds__(256) void fill_kernel(
    const int* __restrict__ esrc, const int* __restrict__ edst, int E, int Et,
    int* __restrict__ cur, int* __restrict__ csr)
{
    int e = blockIdx.x * 256 + threadIdx.x;
    if (e >= Et) return;
    int s, d;
    if (e < E) { s = esrc[e]; d = edst[e]; } else { s = d = e - E; }
    int pos = atomicAdd(&cur[d], 1);
    csr[pos] = s;
}

// ---------------- fused GAT aggregation (gather, deterministic) -------------
// one wave per destination node; lane i owns features i and i+64.
__global__ __launch_bounds__(256) void gat_gather_kernel(
    const float* __restrict__ H, const int* __restrict__ csr,
    const int* __restrict__ offs, const int* __restrict__ cnt,
    const float* __restrict__ as, const float* __restrict__ ad,
    const float* __restrict__ bias, float* __restrict__ out, int N)
{
    int d = blockIdx.x * 4 + (threadIdx.x >> 6);
    if (d >= N) return;
    int lane = threadIdx.x & 63;
    int start = offs[d];
    int deg = cnt[d];
    float ad0 = ad[d * 4 + 0], ad1 = ad[d * 4 + 1];
    float ad2 = ad[d * 4 + 2], ad3 = ad[d * 4 + 3];

    // pass 1: per-head running max of leaky_relu(as[s]+ad[d])
    float m0 = -INFINITY, m1 = -INFINITY, m2 = -INFINITY, m3 = -INFINITY;
    for (int k = 0; k < deg; ++k) {
        int s = csr[start + k];
        float e0 = as[s * 4 + 0] + ad0; e0 = e0 > 0.f ? e0 : NEG_SLOPE * e0;
        float e1 = as[s * 4 + 1] + ad1; e1 = e1 > 0.f ? e1 : NEG_SLOPE * e1;
        float e2 = as[s * 4 + 2] + ad2; e2 = e2 > 0.f ? e2 : NEG_SLOPE * e2;
        float e3 = as[s * 4 + 3] + ad3; e3 = e3 > 0.f ? e3 : NEG_SLOPE * e3;
        m0 = fmaxf(m0, e0); m1 = fmaxf(m1, e1);
        m2 = fmaxf(m2, e2); m3 = fmaxf(m3, e3);
    }

    // pass 2: accumulate unnormalized sums in f64
    double s0 = 0, s1 = 0, s2 = 0, s3 = 0, acc0 = 0, acc1 = 0;
    int hsel = lane >> 5;     // 0: heads (0,2); 1: heads (1,3)
    for (int k = 0; k < deg; ++k) {
        int s = csr[start + k];
        float e0 = as[s * 4 + 0] + ad0; e0 = e0 > 0.f ? e0 : NEG_SLOPE * e0;
        float e1 = as[s * 4 + 1] + ad1; e1 = e1 > 0.f ? e1 : NEG_SLOPE * e1;
        float e2 = as[s * 4 + 2] + ad2; e2 = e2 > 0.f ? e2 : NEG_SLOPE * e2;
        float e3 = as[s * 4 + 3] + ad3; e3 = e3 > 0.f ? e3 : NEG_SLOPE * e3;
        float w0 = expf(e0 - m0), w1 = expf(e1 - m1);
        float w2 = expf(e2 - m2), w3 = expf(e3 - m3);
        s0 += (double)w0; s1 += (double)w1; s2 += (double)w2; s3 += (double)w3;
        float wlo = hsel ? w1 : w0;
        float whi = hsel ? w3 : w2;
        const float* hrow = H + (size_t)s * 128;
        acc0 += (double)wlo * (double)hrow[lane];
        acc1 += (double)whi * (double)hrow[lane + 64];
    }
    double dlo = (hsel ? s1 : s0) + 1e-16;
    double dhi = (hsel ? s3 : s2) + 1e-16;
    float o0 = (float)(acc0 / dlo) + bias[lane];
    float o1 = (float)(acc1 / dhi) + bias[lane + 64];
    out[(size_t)d * 128 + lane]      = fmaxf(o0, 0.f);
    out[(size_t)d * 128 + lane + 64] = fmaxf(o1, 0.f);
}

// ---------------- classifier head -------------------------------------------
__global__ __launch_bounds__(256) void classifier_kernel(
    const float* __restrict__ X, const float* __restrict__ Wc1,
    const float* __restrict__ bc1, const float* __restrict__ Wc2,
    const float* __restrict__ bc2, float* __restrict__ out, int N)
{
    int n = blockIdx.x * 8 + (threadIdx.x >> 5);
    if (n >= N) return;
    int j = threadIdx.x & 31;
    const float* xrow = X + (size_t)n * 128;
    double acc = (double)bc1[j];
    #pragma unroll 8
    for (int k = 0; k < 128; ++k)
        acc += (double)xrow[k] * (double)Wc1[k * 32 + j];
    double y = acc * (double)Wc2[j];
    #pragma unroll
    for (int off = 16; off; off >>= 1) y += __shfl_xor(y, off, 64);
    if (j == 0) {
        double z = y + (double)bc2[0];
        out[n] = (float)(1.0 / (1.0 + exp(-z)));
    }
}

extern "C" void kernel_launch(void* const* d_in, const int* in_sizes, int n_in,
                              void* d_out, int out_size, void* d_ws, size_t ws_size,
                              hipStream_t stream)
{
    const float* x      = (const float*)d_in[0];
    const int*   eidx   = (const int*)d_in[1];
    const float* W1     = (const float*)d_in[2];
    const float* a_src1 = (const float*)d_in[3];
    const float* a_dst1 = (const float*)d_in[4];
    const float* b1     = (const float*)d_in[5];
    const float* W2     = (const float*)d_in[6];
    const float* a_src2 = (const float*)d_in[7];
    const float* a_dst2 = (const float*)d_in[8];
    const float* b2     = (const float*)d_in[9];
    const float* Wc1    = (const float*)d_in[10];
    const float* bc1    = (const float*)d_in[11];
    const float* Wc2    = (const float*)d_in[12];
    const float* bc2    = (const float*)d_in[13];

    int N  = in_sizes[0] / 128;
    int E  = in_sizes[1] / 2;
    int Et = E + N;
    const int* esrc = eidx;
    const int* edst = eidx + E;

    char* wsb = (char*)d_ws;
    float* h_buf  = (float*)wsb;              wsb += (size_t)N * 128 * 4;
    float* f1_buf = (float*)wsb;              wsb += (size_t)N * 128 * 4;
    float* as_buf = (float*)wsb;              wsb += (size_t)N * 4 * 4;
    float* ad_buf = (float*)wsb;              wsb += (size_t)N * 4 * 4;
    int*   cnt    = (int*)wsb;                wsb += (size_t)N * 4;
    int*   offs   = (int*)wsb;                wsb += (size_t)N * 4;
    int*   cur    = (int*)wsb;                wsb += (size_t)N * 4;
    int*   bsum   = (int*)wsb;                wsb += 512 * 4;
    int*   csr    = (int*)wsb;                wsb += (size_t)Et * 4;

    int nbN = (N + 255) / 256;
    int nbE = (Et + 255) / 256;

    // ---- build CSR by destination (shared by both layers) ----
    zero_int_kernel<<<nbN, 256, 0, stream>>>(cnt, N);
    count_kernel<<<nbE, 256, 0, stream>>>(edst, E, Et, cnt);
    scan_block_kernel<<<nbN, 256, 0, stream>>>(cnt, offs, bsum, N);
    scan_block_kernel<<<1, 256, 0, stream>>>(bsum, bsum, &bsum[300], nbN);
    scan_add_kernel<<<nbN, 256, 0, stream>>>(offs, bsum, N);
    copy_int_kernel<<<nbN, 256, 0, stream>>>(offs, cur, N);
    fill_kernel<<<nbE, 256, 0, stream>>>(esrc, edst, E, Et, cur, csr);

    // ---- layer 1: x -> f1 ----
    gemm128_kernel<<<(N + 7) / 8, 256, 0, stream>>>(x, W1, h_buf, N);
    alpha_kernel<<<(N + 1) / 2, 256, 0, stream>>>(h_buf, a_src1, a_dst1, as_buf, ad_buf, N);
    gat_gather_kernel<<<(N + 3) / 4, 256, 0, stream>>>(h_buf, csr, offs, cnt,
                                                       as_buf, ad_buf, b1, f1_buf, N);
    // ---- layer 2: f1 -> f1 (in place via h_buf) ----
    gemm128_kernel<<<(N + 7) / 8, 256, 0, stream>>>(f1_buf, W2, h_buf, N);
    alpha_kernel<<<(N + 1) / 2, 256, 0, stream>>>(h_buf, a_src2, a_dst2, as_buf, ad_buf, N);
    gat_gather_kernel<<<(N + 3) / 4, 256, 0, stream>>>(h_buf, csr, offs, cnt,
                                                       as_buf, ad_buf, b2, f1_buf, N);

    // ---- classifier head -> d_out [N] ----
    classifier_kernel<<<(N + 7) / 8, 256, 0, stream>>>(f1_buf, Wc1, bc1, Wc2, bc2,
                                                       (float*)d_out, N);
}

// Round 5
// 684.155 us; speedup vs baseline: 1.3468x; 1.3468x over previous
//
#include <hip/hip_runtime.h>
#include <hip/hip_bf16.h>
#include <math.h>

#define NEG_SLOPE 0.2f

// ---------------- GEMM: H = X @ W  (X:[N,128], W:[128,128]) -----------------
// 256 threads = 8 rows x 32 col-groups; each thread does 4 output cols.
__global__ __launch_bounds__(256) void gemm128_kernel(
    const float* __restrict__ X, const float* __restrict__ W,
    float* __restrict__ Hout, int N)
{
    int n  = blockIdx.x * 8 + (threadIdx.x >> 5);
    int j0 = (threadIdx.x & 31) * 4;
    if (n >= N) return;
    const float* xrow = X + (size_t)n * 128;
    float a0 = 0.f, a1 = 0.f, a2 = 0.f, a3 = 0.f;
    #pragma unroll 8
    for (int k = 0; k < 128; ++k) {
        float xv = xrow[k];
        float4 w = *(const float4*)(W + k * 128 + j0);
        a0 = fmaf(xv, w.x, a0); a1 = fmaf(xv, w.y, a1);
        a2 = fmaf(xv, w.z, a2); a3 = fmaf(xv, w.w, a3);
    }
    *(float4*)(Hout + (size_t)n * 128 + j0) = make_float4(a0, a1, a2, a3);
}

// ---------------- alpha dots: as[n,h], ad[n,h] ------------------------------
__global__ __launch_bounds__(256) void alpha_kernel(
    const float* __restrict__ H, const float* __restrict__ a_src,
    const float* __restrict__ a_dst, float* __restrict__ as_out,
    float* __restrict__ ad_out, int N)
{
    int n = blockIdx.x * 2 + (threadIdx.x >> 7);
    if (n >= N) return;
    int i = threadIdx.x & 127;
    float hv = H[(size_t)n * 128 + i];
    float ps = hv * a_src[i];
    float pd = hv * a_dst[i];
    #pragma unroll
    for (int off = 16; off; off >>= 1) {   // reduce within 32-lane head group
        ps += __shfl_xor(ps, off, 64);
        pd += __shfl_xor(pd, off, 64);
    }
    if ((i & 31) == 0) {
        as_out[n * 4 + (i >> 5)] = ps;
        ad_out[n * 4 + (i >> 5)] = pd;
    }
}

// ---------------- CSR build helpers -----------------------------------------
__global__ __launch_bounds__(256) void zero_int_kernel(int* __restrict__ p, int n)
{
    int i = blockIdx.x * 256 + threadIdx.x;
    if (i < n) p[i] = 0;
}

__global__ __launch_bounds__(256) void copy_int_kernel(
    const int* __restrict__ src, int* __restrict__ dst, int n)
{
    int i = blockIdx.x * 256 + threadIdx.x;
    if (i < n) dst[i] = src[i];
}

__global__ __launch_bounds__(256) void count_kernel(
    const int* __restrict__ edst, int E, int Et, int* __restrict__ cnt)
{
    int e = blockIdx.x * 256 + threadIdx.x;
    if (e >= Et) return;
    int d = (e < E) ? edst[e] : (e - E);
    atomicAdd(&cnt[d], 1);
}

// exclusive scan within each 256-block; bsum[b] = block total
__global__ __launch_bounds__(256) void scan_block_kernel(
    const int* __restrict__ in, int* __restrict__ out,
    int* __restrict__ bsum, int n)
{
    __shared__ int sh[256];
    int i = blockIdx.x * 256 + threadIdx.x;
    int v = (i < n) ? in[i] : 0;
    sh[threadIdx.x] = v;
    __syncthreads();
    #pragma unroll
    for (int off = 1; off < 256; off <<= 1) {
        int t = 0;
        if (threadIdx.x >= off) t = sh[threadIdx.x - off];
        __syncthreads();
        if (threadIdx.x >= off) sh[threadIdx.x] += t;
        __syncthreads();
    }
    if (i < n) out[i] = sh[threadIdx.x] - v;        // exclusive
    if (threadIdx.x == 255) bsum[blockIdx.x] = sh[255];
}

__global__ __launch_bounds__(256) void scan_add_kernel(
    int* __restrict__ offs, const int* __restrict__ bsum, int n)
{
    int i = blockIdx.x * 256 + threadIdx.x;
    if (i < n) offs[i] += bsum[blockIdx.x];
}

__global__ __launch_bounds__(256) void fill_kernel(
    const int* __restrict__ esrc, const int* __restrict__ edst, int E, int Et,
    int* __restrict__ cur, int* __restrict__ csr)
{
    int e = blockIdx.x * 256 + threadIdx.x;
    if (e >= Et) return;
    int s, d;
    if (e < E) { s = esrc[e]; d = edst[e]; } else { s = d = e - E; }
    int pos = atomicAdd(&cur[d], 1);
    csr[pos] = s;
}

// ---------------- edge softmax: per-edge exp weights + per-node 1/sum -------
// one wave per destination node; lanes stride over incident edges.
// wbuf layout: per edge, 2 x float2: [e*2+0] = {w_h0, w_h2}, [e*2+1] = {w_h1, w_h3}
__global__ __launch_bounds__(256) void edge_softmax_kernel(
    const float* __restrict__ as, const float* __restrict__ ad,
    const int* __restrict__ csr, const int* __restrict__ offs,
    const int* __restrict__ cnt, float2* __restrict__ wbuf,
    float4* __restrict__ inv_s, int N)
{
    int d = blockIdx.x * 4 + (threadIdx.x >> 6);
    if (d >= N) return;
    int lane = threadIdx.x & 63;
    int start = offs[d];
    int deg = cnt[d];
    float4 adv = *(const float4*)(ad + d * 4);

    float m0 = -INFINITY, m1 = -INFINITY, m2 = -INFINITY, m3 = -INFINITY;
    for (int k = lane; k < deg; k += 64) {
        int s = csr[start + k];
        float4 av = *(const float4*)(as + s * 4);
        float e0 = av.x + adv.x; e0 = e0 > 0.f ? e0 : NEG_SLOPE * e0;
        float e1 = av.y + adv.y; e1 = e1 > 0.f ? e1 : NEG_SLOPE * e1;
        float e2 = av.z + adv.z; e2 = e2 > 0.f ? e2 : NEG_SLOPE * e2;
        float e3 = av.w + adv.w; e3 = e3 > 0.f ? e3 : NEG_SLOPE * e3;
        m0 = fmaxf(m0, e0); m1 = fmaxf(m1, e1);
        m2 = fmaxf(m2, e2); m3 = fmaxf(m3, e3);
    }
    #pragma unroll
    for (int off = 32; off; off >>= 1) {
        m0 = fmaxf(m0, __shfl_xor(m0, off, 64));
        m1 = fmaxf(m1, __shfl_xor(m1, off, 64));
        m2 = fmaxf(m2, __shfl_xor(m2, off, 64));
        m3 = fmaxf(m3, __shfl_xor(m3, off, 64));
    }

    float s0 = 0.f, s1 = 0.f, s2 = 0.f, s3 = 0.f;
    for (int k = lane; k < deg; k += 64) {
        int s = csr[start + k];
        float4 av = *(const float4*)(as + s * 4);
        float e0 = av.x + adv.x; e0 = e0 > 0.f ? e0 : NEG_SLOPE * e0;
        float e1 = av.y + adv.y; e1 = e1 > 0.f ? e1 : NEG_SLOPE * e1;
        float e2 = av.z + adv.z; e2 = e2 > 0.f ? e2 : NEG_SLOPE * e2;
        float e3 = av.w + adv.w; e3 = e3 > 0.f ? e3 : NEG_SLOPE * e3;
        float w0 = expf(e0 - m0), w1 = expf(e1 - m1);
        float w2 = expf(e2 - m2), w3 = expf(e3 - m3);
        wbuf[(size_t)(start + k) * 2 + 0] = make_float2(w0, w2);
        wbuf[(size_t)(start + k) * 2 + 1] = make_float2(w1, w3);
        s0 += w0; s1 += w1; s2 += w2; s3 += w3;
    }
    #pragma unroll
    for (int off = 32; off; off >>= 1) {
        s0 += __shfl_xor(s0, off, 64);
        s1 += __shfl_xor(s1, off, 64);
        s2 += __shfl_xor(s2, off, 64);
        s3 += __shfl_xor(s3, off, 64);
    }
    if (lane == 0)
        inv_s[d] = make_float4(1.f / (s0 + 1e-16f), 1.f / (s1 + 1e-16f),
                               1.f / (s2 + 1e-16f), 1.f / (s3 + 1e-16f));
}

// ---------------- fused GAT aggregation (gather, lean inner loop) -----------
// one wave per destination node; lane i owns features i (heads 0/1) and
// i+64 (heads 2/3). hsel = lane>>5 picks which head of each pair.
__global__ __launch_bounds__(256) void gat_gather_kernel(
    const float* __restrict__ H, const int* __restrict__ csr,
    const int* __restrict__ offs, const int* __restrict__ cnt,
    const float2* __restrict__ wbuf, const float4* __restrict__ inv_s,
    const float* __restrict__ bias, float* __restrict__ out, int N)
{
    int d = blockIdx.x * 4 + (threadIdx.x >> 6);
    if (d >= N) return;
    int lane = threadIdx.x & 63;
    int start = offs[d];
    int deg = cnt[d];
    int hsel = lane >> 5;

    float acc0 = 0.f, acc1 = 0.f;
    #pragma unroll 2
    for (int k = 0; k < deg; ++k) {
        int s = csr[start + k];
        float2 w = wbuf[(size_t)(start + k) * 2 + hsel];
        const float* hrow = H + (size_t)s * 128;
        acc0 = fmaf(w.x, hrow[lane], acc0);
        acc1 = fmaf(w.y, hrow[lane + 64], acc1);
    }
    float4 inv = inv_s[d];
    float ilo = hsel ? inv.y : inv.x;
    float ihi = hsel ? inv.w : inv.z;
    float o0 = acc0 * ilo + bias[lane];
    float o1 = acc1 * ihi + bias[lane + 64];
    out[(size_t)d * 128 + lane]      = fmaxf(o0, 0.f);
    out[(size_t)d * 128 + lane + 64] = fmaxf(o1, 0.f);
}

// ---------------- classifier head -------------------------------------------
__global__ __launch_bounds__(256) void classifier_kernel(
    const float* __restrict__ X, const float* __restrict__ Wc1,
    const float* __restrict__ bc1, const float* __restrict__ Wc2,
    const float* __restrict__ bc2, float* __restrict__ out, int N)
{
    int n = blockIdx.x * 8 + (threadIdx.x >> 5);
    if (n >= N) return;
    int j = threadIdx.x & 31;
    const float* xrow = X + (size_t)n * 128;
    float acc = bc1[j];
    #pragma unroll 8
    for (int k = 0; k < 128; ++k)
        acc = fmaf(xrow[k], Wc1[k * 32 + j], acc);
    float y = acc * Wc2[j];
    #pragma unroll
    for (int off = 16; off; off >>= 1) y += __shfl_xor(y, off, 64);
    if (j == 0)
        out[n] = 1.0f / (1.0f + expf(-(y + bc2[0])));
}

extern "C" void kernel_launch(void* const* d_in, const int* in_sizes, int n_in,
                              void* d_out, int out_size, void* d_ws, size_t ws_size,
                              hipStream_t stream)
{
    const float* x      = (const float*)d_in[0];
    const int*   eidx   = (const int*)d_in[1];
    const float* W1     = (const float*)d_in[2];
    const float* a_src1 = (const float*)d_in[3];
    const float* a_dst1 = (const float*)d_in[4];
    const float* b1     = (const float*)d_in[5];
    const float* W2     = (const float*)d_in[6];
    const float* a_src2 = (const float*)d_in[7];
    const float* a_dst2 = (const float*)d_in[8];
    const float* b2     = (const float*)d_in[9];
    const float* Wc1    = (const float*)d_in[10];
    const float* bc1    = (const float*)d_in[11];
    const float* Wc2    = (const float*)d_in[12];
    const float* bc2    = (const float*)d_in[13];

    int N  = in_sizes[0] / 128;
    int E  = in_sizes[1] / 2;
    int Et = E + N;
    const int* esrc = eidx;
    const int* edst = eidx + E;

    char* wsb = (char*)d_ws;
    float*  h_buf  = (float*)wsb;   wsb += (size_t)N * 128 * 4;
    float*  f1_buf = (float*)wsb;   wsb += (size_t)N * 128 * 4;
    float*  as_buf = (float*)wsb;   wsb += (size_t)N * 4 * 4;
    float*  ad_buf = (float*)wsb;   wsb += (size_t)N * 4 * 4;
    float4* invs   = (float4*)wsb;  wsb += (size_t)N * 16;
    int*    cnt    = (int*)wsb;     wsb += (size_t)N * 4;
    int*    offs   = (int*)wsb;     wsb += (size_t)N * 4;
    int*    cur    = (int*)wsb;     wsb += (size_t)N * 4;
    int*    bsum   = (int*)wsb;     wsb += 512 * 4;
    int*    csr    = (int*)wsb;     wsb += (size_t)Et * 4;
    wsb = (char*)(((size_t)wsb + 15) & ~(size_t)15);
    float2* wbuf   = (float2*)wsb;  wsb += (size_t)Et * 2 * 8;

    int nbN = (N + 255) / 256;
    int nbE = (Et + 255) / 256;

    // ---- build CSR by destination (shared by both layers) ----
    zero_int_kernel<<<nbN, 256, 0, stream>>>(cnt, N);
    count_kernel<<<nbE, 256, 0, stream>>>(edst, E, Et, cnt);
    scan_block_kernel<<<nbN, 256, 0, stream>>>(cnt, offs, bsum, N);
    scan_block_kernel<<<1, 256, 0, stream>>>(bsum, bsum, &bsum[300], nbN);
    scan_add_kernel<<<nbN, 256, 0, stream>>>(offs, bsum, N);
    copy_int_kernel<<<nbN, 256, 0, stream>>>(offs, cur, N);
    fill_kernel<<<nbE, 256, 0, stream>>>(esrc, edst, E, Et, cur, csr);

    // ---- layer 1: x -> f1 ----
    gemm128_kernel<<<(N + 7) / 8, 256, 0, stream>>>(x, W1, h_buf, N);
    alpha_kernel<<<(N + 1) / 2, 256, 0, stream>>>(h_buf, a_src1, a_dst1, as_buf, ad_buf, N);
    edge_softmax_kernel<<<(N + 3) / 4, 256, 0, stream>>>(as_buf, ad_buf, csr, offs, cnt,
                                                         wbuf, invs, N);
    gat_gather_kernel<<<(N + 3) / 4, 256, 0, stream>>>(h_buf, csr, offs, cnt,
                                                       wbuf, invs, b1, f1_buf, N);
    // ---- layer 2: f1 -> f1 ----
    gemm128_kernel<<<(N + 7) / 8, 256, 0, stream>>>(f1_buf, W2, h_buf, N);
    alpha_kernel<<<(N + 1) / 2, 256, 0, stream>>>(h_buf, a_src2, a_dst2, as_buf, ad_buf, N);
    edge_softmax_kernel<<<(N + 3) / 4, 256, 0, stream>>>(as_buf, ad_buf, csr, offs, cnt,
                                                         wbuf, invs, N);
    gat_gather_kernel<<<(N + 3) / 4, 256, 0, stream>>>(h_buf, csr, offs, cnt,
                                                       wbuf, invs, b2, f1_buf, N);

    // ---- classifier head -> d_out [N] ----
    classifier_kernel<<<(N + 7) / 8, 256, 0, stream>>>(f1_buf, Wc1, bc1, Wc2, bc2,
                                                       (float*)d_out, N);
}

// Round 6
// 500.505 us; speedup vs baseline: 1.8409x; 1.3669x over previous
//
#include <hip/hip_runtime.h>
#include <hip/hip_bf16.h>
#include <math.h>

#define NEG_SLOPE 0.2f

// ---------------- fused GEMM + alpha: H = X @ W, as/ad = H . a_src/a_dst ----
// 32 rows per block, 256 threads. Thread t: row-group rg = t>>5 (rows
// rg, rg+8, rg+16, rg+24), col lane c = t&31 (cols 4c..4c+3, all in head c>>3).
// X tile staged in LDS (16 KB contiguous). Inner loop: 1 global float4 (W) +
// 4 broadcast ds_read + 16 FMA. Epilogue computes per-row-head alpha dots via
// 8-lane shuffle reduction (offsets 1,2,4 stay inside the 8-lane head group).
__global__ __launch_bounds__(256) void gemm_alpha_kernel(
    const float* __restrict__ X, const float* __restrict__ W,
    const float* __restrict__ a_src, const float* __restrict__ a_dst,
    float* __restrict__ Hout, float* __restrict__ as_out,
    float* __restrict__ ad_out, int N)
{
    __shared__ float xt[32 * 128];
    int n0 = blockIdx.x * 32;
    int t  = threadIdx.x;

    // stage X tile: rows n0..n0+31 are contiguous -> straight 16 KB copy
    {
        const float4* src = (const float4*)(X + (size_t)n0 * 128);
        float4* dst = (float4*)xt;
        int rows = N - n0; if (rows > 32) rows = 32;
        int maxv = rows * 32;                 // valid float4 count
        #pragma unroll
        for (int i = 0; i < 4; ++i) {
            int idx = t + i * 256;
            int g = idx < maxv ? idx : maxv - 1;   // clamp (partial last block)
            dst[idx] = src[g];
        }
    }
    __syncthreads();

    int rg = t >> 5;
    int c  = t & 31;
    int j0 = c * 4;

    float a00=0.f,a01=0.f,a02=0.f,a03=0.f;
    float a10=0.f,a11=0.f,a12=0.f,a13=0.f;
    float a20=0.f,a21=0.f,a22=0.f,a23=0.f;
    float a30=0.f,a31=0.f,a32=0.f,a33=0.f;

    #pragma unroll 4
    for (int k = 0; k < 128; ++k) {
        float4 w = *(const float4*)(W + k * 128 + j0);
        float x0 = xt[(rg     ) * 128 + k];
        float x1 = xt[(rg +  8) * 128 + k];
        float x2 = xt[(rg + 16) * 128 + k];
        float x3 = xt[(rg + 24) * 128 + k];
        a00 = fmaf(x0, w.x, a00); a01 = fmaf(x0, w.y, a01);
        a02 = fmaf(x0, w.z, a02); a03 = fmaf(x0, w.w, a03);
        a10 = fmaf(x1, w.x, a10); a11 = fmaf(x1, w.y, a11);
        a12 = fmaf(x1, w.z, a12); a13 = fmaf(x1, w.w, a13);
        a20 = fmaf(x2, w.x, a20); a21 = fmaf(x2, w.y, a21);
        a22 = fmaf(x2, w.z, a22); a23 = fmaf(x2, w.w, a23);
        a30 = fmaf(x3, w.x, a30); a31 = fmaf(x3, w.y, a31);
        a32 = fmaf(x3, w.z, a32); a33 = fmaf(x3, w.w, a33);
    }

    float4 asv = *(const float4*)(a_src + j0);
    float4 adv = *(const float4*)(a_dst + j0);
    int head = c >> 3;
    int wlane = (c & 7) == 0;

    #pragma unroll
    for (int rr = 0; rr < 4; ++rr) {
        float b0, b1, b2, b3;
        if (rr == 0) { b0=a00; b1=a01; b2=a02; b3=a03; }
        else if (rr == 1) { b0=a10; b1=a11; b2=a12; b3=a13; }
        else if (rr == 2) { b0=a20; b1=a21; b2=a22; b3=a23; }
        else { b0=a30; b1=a31; b2=a32; b3=a33; }
        int row = n0 + rg + rr * 8;
        bool valid = row < N;
        if (valid)
            *(float4*)(Hout + (size_t)row * 128 + j0) = make_float4(b0, b1, b2, b3);
        float ps = b0*asv.x + b1*asv.y + b2*asv.z + b3*asv.w;
        float pd = b0*adv.x + b1*adv.y + b2*adv.z + b3*adv.w;
        ps += __shfl_xor(ps, 1, 64); pd += __shfl_xor(pd, 1, 64);
        ps += __shfl_xor(ps, 2, 64); pd += __shfl_xor(pd, 2, 64);
        ps += __shfl_xor(ps, 4, 64); pd += __shfl_xor(pd, 4, 64);
        if (wlane && valid) {
            as_out[row * 4 + head] = ps;
            ad_out[row * 4 + head] = pd;
        }
    }
}

// ---------------- CSR build helpers -----------------------------------------
__global__ __launch_bounds__(256) void zero_int_kernel(int* __restrict__ p, int n)
{
    int i = blockIdx.x * 256 + threadIdx.x;
    if (i < n) p[i] = 0;
}

__global__ __launch_bounds__(256) void copy_int_kernel(
    const int* __restrict__ src, int* __restrict__ dst, int n)
{
    int i = blockIdx.x * 256 + threadIdx.x;
    if (i < n) dst[i] = src[i];
}

__global__ __launch_bounds__(256) void count_kernel(
    const int* __restrict__ edst, int E, int Et, int* __restrict__ cnt)
{
    int e = blockIdx.x * 256 + threadIdx.x;
    if (e >= Et) return;
    int d = (e < E) ? edst[e] : (e - E);
    atomicAdd(&cnt[d], 1);
}

// exclusive scan within each 256-block; bsum[b] = block total
__global__ __launch_bounds__(256) void scan_block_kernel(
    const int* __restrict__ in, int* __restrict__ out,
    int* __restrict__ bsum, int n)
{
    __shared__ int sh[256];
    int i = blockIdx.x * 256 + threadIdx.x;
    int v = (i < n) ? in[i] : 0;
    sh[threadIdx.x] = v;
    __syncthreads();
    #pragma unroll
    for (int off = 1; off < 256; off <<= 1) {
        int t = 0;
        if (threadIdx.x >= off) t = sh[threadIdx.x - off];
        __syncthreads();
        if (threadIdx.x >= off) sh[threadIdx.x] += t;
        __syncthreads();
    }
    if (i < n) out[i] = sh[threadIdx.x] - v;        // exclusive
    if (threadIdx.x == 255) bsum[blockIdx.x] = sh[255];
}

__global__ __launch_bounds__(256) void scan_add_kernel(
    int* __restrict__ offs, const int* __restrict__ bsum, int n)
{
    int i = blockIdx.x * 256 + threadIdx.x;
    if (i < n) offs[i] += bsum[blockIdx.x];
}

__global__ __launch_bounds__(256) void fill_kernel(
    const int* __restrict__ esrc, const int* __restrict__ edst, int E, int Et,
    int* __restrict__ cur, int* __restrict__ csr)
{
    int e = blockIdx.x * 256 + threadIdx.x;
    if (e >= Et) return;
    int s, d;
    if (e < E) { s = esrc[e]; d = edst[e]; } else { s = d = e - E; }
    int pos = atomicAdd(&cur[d], 1);
    csr[pos] = s;
}

// ---------------- edge softmax: per-edge exp weights + per-node 1/sum -------
// one wave per destination node; lanes stride over incident edges.
// wbuf layout: per edge, 2 x float2: [e*2+0] = {w_h0, w_h2}, [e*2+1] = {w_h1, w_h3}
__global__ __launch_bounds__(256) void edge_softmax_kernel(
    const float* __restrict__ as, const float* __restrict__ ad,
    const int* __restrict__ csr, const int* __restrict__ offs,
    const int* __restrict__ cnt, float2* __restrict__ wbuf,
    float4* __restrict__ inv_s, int N)
{
    int d = blockIdx.x * 4 + (threadIdx.x >> 6);
    if (d >= N) return;
    int lane = threadIdx.x & 63;
    int start = offs[d];
    int deg = cnt[d];
    float4 adv = *(const float4*)(ad + d * 4);

    float m0 = -INFINITY, m1 = -INFINITY, m2 = -INFINITY, m3 = -INFINITY;
    for (int k = lane; k < deg; k += 64) {
        int s = csr[start + k];
        float4 av = *(const float4*)(as + s * 4);
        float e0 = av.x + adv.x; e0 = e0 > 0.f ? e0 : NEG_SLOPE * e0;
        float e1 = av.y + adv.y; e1 = e1 > 0.f ? e1 : NEG_SLOPE * e1;
        float e2 = av.z + adv.z; e2 = e2 > 0.f ? e2 : NEG_SLOPE * e2;
        float e3 = av.w + adv.w; e3 = e3 > 0.f ? e3 : NEG_SLOPE * e3;
        m0 = fmaxf(m0, e0); m1 = fmaxf(m1, e1);
        m2 = fmaxf(m2, e2); m3 = fmaxf(m3, e3);
    }
    #pragma unroll
    for (int off = 32; off; off >>= 1) {
        m0 = fmaxf(m0, __shfl_xor(m0, off, 64));
        m1 = fmaxf(m1, __shfl_xor(m1, off, 64));
        m2 = fmaxf(m2, __shfl_xor(m2, off, 64));
        m3 = fmaxf(m3, __shfl_xor(m3, off, 64));
    }

    float s0 = 0.f, s1 = 0.f, s2 = 0.f, s3 = 0.f;
    for (int k = lane; k < deg; k += 64) {
        int s = csr[start + k];
        float4 av = *(const float4*)(as + s * 4);
        float e0 = av.x + adv.x; e0 = e0 > 0.f ? e0 : NEG_SLOPE * e0;
        float e1 = av.y + adv.y; e1 = e1 > 0.f ? e1 : NEG_SLOPE * e1;
        float e2 = av.z + adv.z; e2 = e2 > 0.f ? e2 : NEG_SLOPE * e2;
        float e3 = av.w + adv.w; e3 = e3 > 0.f ? e3 : NEG_SLOPE * e3;
        float w0 = expf(e0 - m0), w1 = expf(e1 - m1);
        float w2 = expf(e2 - m2), w3 = expf(e3 - m3);
        wbuf[(size_t)(start + k) * 2 + 0] = make_float2(w0, w2);
        wbuf[(size_t)(start + k) * 2 + 1] = make_float2(w1, w3);
        s0 += w0; s1 += w1; s2 += w2; s3 += w3;
    }
    #pragma unroll
    for (int off = 32; off; off >>= 1) {
        s0 += __shfl_xor(s0, off, 64);
        s1 += __shfl_xor(s1, off, 64);
        s2 += __shfl_xor(s2, off, 64);
        s3 += __shfl_xor(s3, off, 64);
    }
    if (lane == 0)
        inv_s[d] = make_float4(1.f / (s0 + 1e-16f), 1.f / (s1 + 1e-16f),
                               1.f / (s2 + 1e-16f), 1.f / (s3 + 1e-16f));
}

// ---------------- fused GAT aggregation (gather, lean inner loop) -----------
// one wave per destination node; lane i owns features i (heads 0/1) and
// i+64 (heads 2/3). hsel = lane>>5 picks which head of each pair.
__global__ __launch_bounds__(256) void gat_gather_kernel(
    const float* __restrict__ H, const int* __restrict__ csr,
    const int* __restrict__ offs, const int* __restrict__ cnt,
    const float2* __restrict__ wbuf, const float4* __restrict__ inv_s,
    const float* __restrict__ bias, float* __restrict__ out, int N)
{
    int d = blockIdx.x * 4 + (threadIdx.x >> 6);
    if (d >= N) return;
    int lane = threadIdx.x & 63;
    int start = offs[d];
    int deg = cnt[d];
    int hsel = lane >> 5;

    float acc0 = 0.f, acc1 = 0.f;
    #pragma unroll 2
    for (int k = 0; k < deg; ++k) {
        int s = csr[start + k];
        float2 w = wbuf[(size_t)(start + k) * 2 + hsel];
        const float* hrow = H + (size_t)s * 128;
        acc0 = fmaf(w.x, hrow[lane], acc0);
        acc1 = fmaf(w.y, hrow[lane + 64], acc1);
    }
    float4 inv = inv_s[d];
    float ilo = hsel ? inv.y : inv.x;
    float ihi = hsel ? inv.w : inv.z;
    float o0 = acc0 * ilo + bias[lane];
    float o1 = acc1 * ihi + bias[lane + 64];
    out[(size_t)d * 128 + lane]      = fmaxf(o0, 0.f);
    out[(size_t)d * 128 + lane + 64] = fmaxf(o1, 0.f);
}

// ---------------- classifier head -------------------------------------------
__global__ __launch_bounds__(256) void classifier_kernel(
    const float* __restrict__ X, const float* __restrict__ Wc1,
    const float* __restrict__ bc1, const float* __restrict__ Wc2,
    const float* __restrict__ bc2, float* __restrict__ out, int N)
{
    int n = blockIdx.x * 8 + (threadIdx.x >> 5);
    if (n >= N) return;
    int j = threadIdx.x & 31;
    const float* xrow = X + (size_t)n * 128;
    float acc = bc1[j];
    #pragma unroll 8
    for (int k = 0; k < 128; ++k)
        acc = fmaf(xrow[k], Wc1[k * 32 + j], acc);
    float y = acc * Wc2[j];
    #pragma unroll
    for (int off = 16; off; off >>= 1) y += __shfl_xor(y, off, 64);
    if (j == 0)
        out[n] = 1.0f / (1.0f + expf(-(y + bc2[0])));
}

extern "C" void kernel_launch(void* const* d_in, const int* in_sizes, int n_in,
                              void* d_out, int out_size, void* d_ws, size_t ws_size,
                              hipStream_t stream)
{
    const float* x      = (const float*)d_in[0];
    const int*   eidx   = (const int*)d_in[1];
    const float* W1     = (const float*)d_in[2];
    const float* a_src1 = (const float*)d_in[3];
    const float* a_dst1 = (const float*)d_in[4];
    const float* b1     = (const float*)d_in[5];
    const float* W2     = (const float*)d_in[6];
    const float* a_src2 = (const float*)d_in[7];
    const float* a_dst2 = (const float*)d_in[8];
    const float* b2     = (const float*)d_in[9];
    const float* Wc1    = (const float*)d_in[10];
    const float* bc1    = (const float*)d_in[11];
    const float* Wc2    = (const float*)d_in[12];
    const float* bc2    = (const float*)d_in[13];

    int N  = in_sizes[0] / 128;
    int E  = in_sizes[1] / 2;
    int Et = E + N;
    const int* esrc = eidx;
    const int* edst = eidx + E;

    char* wsb = (char*)d_ws;
    float*  h_buf  = (float*)wsb;   wsb += (size_t)N * 128 * 4;
    float*  f1_buf = (float*)wsb;   wsb += (size_t)N * 128 * 4;
    float*  as_buf = (float*)wsb;   wsb += (size_t)N * 4 * 4;
    float*  ad_buf = (float*)wsb;   wsb += (size_t)N * 4 * 4;
    float4* invs   = (float4*)wsb;  wsb += (size_t)N * 16;
    int*    cnt    = (int*)wsb;     wsb += (size_t)N * 4;
    int*    offs   = (int*)wsb;     wsb += (size_t)N * 4;
    int*    cur    = (int*)wsb;     wsb += (size_t)N * 4;
    int*    bsum   = (int*)wsb;     wsb += 512 * 4;
    int*    csr    = (int*)wsb;     wsb += (size_t)Et * 4;
    wsb = (char*)(((size_t)wsb + 15) & ~(size_t)15);
    float2* wbuf   = (float2*)wsb;  wsb += (size_t)Et * 2 * 8;

    int nbN = (N + 255) / 256;
    int nbE = (Et + 255) / 256;

    // ---- build CSR by destination (shared by both layers) ----
    zero_int_kernel<<<nbN, 256, 0, stream>>>(cnt, N);
    count_kernel<<<nbE, 256, 0, stream>>>(edst, E, Et, cnt);
    scan_block_kernel<<<nbN, 256, 0, stream>>>(cnt, offs, bsum, N);
    scan_block_kernel<<<1, 256, 0, stream>>>(bsum, bsum, &bsum[300], nbN);
    scan_add_kernel<<<nbN, 256, 0, stream>>>(offs, bsum, N);
    copy_int_kernel<<<nbN, 256, 0, stream>>>(offs, cur, N);
    fill_kernel<<<nbE, 256, 0, stream>>>(esrc, edst, E, Et, cur, csr);

    // ---- layer 1: x -> f1 ----
    gemm_alpha_kernel<<<(N + 31) / 32, 256, 0, stream>>>(x, W1, a_src1, a_dst1,
                                                         h_buf, as_buf, ad_buf, N);
    edge_softmax_kernel<<<(N + 3) / 4, 256, 0, stream>>>(as_buf, ad_buf, csr, offs, cnt,
                                                         wbuf, invs, N);
    gat_gather_kernel<<<(N + 3) / 4, 256, 0, stream>>>(h_buf, csr, offs, cnt,
                                                       wbuf, invs, b1, f1_buf, N);
    // ---- layer 2: f1 -> f1 ----
    gemm_alpha_kernel<<<(N + 31) / 32, 256, 0, stream>>>(f1_buf, W2, a_src2, a_dst2,
                                                         h_buf, as_buf, ad_buf, N);
    edge_softmax_kernel<<<(N + 3) / 4, 256, 0, stream>>>(as_buf, ad_buf, csr, offs, cnt,
                                                         wbuf, invs, N);
    gat_gather_kernel<<<(N + 3) / 4, 256, 0, stream>>>(h_buf, csr, offs, cnt,
                                                       wbuf, invs, b2, f1_buf, N);

    // ---- classifier head -> d_out [N] ----
    classifier_kernel<<<(N + 7) / 8, 256, 0, stream>>>(f1_buf, Wc1, bc1, Wc2, bc2,
                                                       (float*)d_out, N);
}

// Round 7
// 400.771 us; speedup vs baseline: 2.2991x; 1.2489x over previous
//
#include <hip/hip_runtime.h>
#include <hip/hip_bf16.h>
#include <math.h>

#define NEG_SLOPE 0.2f

__device__ __forceinline__ unsigned short f2bf(float f) {
    unsigned int u = __float_as_uint(f);
    u = (u + 0x7fffu + ((u >> 16) & 1u)) >> 16;      // round-to-nearest-even
    return (unsigned short)u;
}
__device__ __forceinline__ float bf2f(unsigned short u) {
    return __uint_as_float((unsigned int)u << 16);
}

// ---------------- fused GEMM + alpha: Hb(bf16) = X @ W, as/ad dots ----------
// 32 rows per block, 256 threads. Thread t: row-group rg = t>>5 (rows
// rg, rg+8, rg+16, rg+24), col lane c = t&31 (cols 4c..4c+3, head c>>3).
// X tile staged in LDS. Epilogue: bf16-pack H row chunk (8B store) and
// per-row-head alpha dots via 8-lane shuffle reduction.
__global__ __launch_bounds__(256) void gemm_alpha_kernel(
    const float* __restrict__ X, const float* __restrict__ W,
    const float* __restrict__ a_src, const float* __restrict__ a_dst,
    unsigned short* __restrict__ Hb, float* __restrict__ as_out,
    float* __restrict__ ad_out, int N)
{
    __shared__ float xt[32 * 128];
    int n0 = blockIdx.x * 32;
    int t  = threadIdx.x;

    {
        const float4* src = (const float4*)(X + (size_t)n0 * 128);
        float4* dst = (float4*)xt;
        int rows = N - n0; if (rows > 32) rows = 32;
        int maxv = rows * 32;
        #pragma unroll
        for (int i = 0; i < 4; ++i) {
            int idx = t + i * 256;
            int g = idx < maxv ? idx : maxv - 1;
            dst[idx] = src[g];
        }
    }
    __syncthreads();

    int rg = t >> 5;
    int c  = t & 31;
    int j0 = c * 4;

    float a00=0.f,a01=0.f,a02=0.f,a03=0.f;
    float a10=0.f,a11=0.f,a12=0.f,a13=0.f;
    float a20=0.f,a21=0.f,a22=0.f,a23=0.f;
    float a30=0.f,a31=0.f,a32=0.f,a33=0.f;

    #pragma unroll 4
    for (int k = 0; k < 128; ++k) {
        float4 w = *(const float4*)(W + k * 128 + j0);
        float x0 = xt[(rg     ) * 128 + k];
        float x1 = xt[(rg +  8) * 128 + k];
        float x2 = xt[(rg + 16) * 128 + k];
        float x3 = xt[(rg + 24) * 128 + k];
        a00 = fmaf(x0, w.x, a00); a01 = fmaf(x0, w.y, a01);
        a02 = fmaf(x0, w.z, a02); a03 = fmaf(x0, w.w, a03);
        a10 = fmaf(x1, w.x, a10); a11 = fmaf(x1, w.y, a11);
        a12 = fmaf(x1, w.z, a12); a13 = fmaf(x1, w.w, a13);
        a20 = fmaf(x2, w.x, a20); a21 = fmaf(x2, w.y, a21);
        a22 = fmaf(x2, w.z, a22); a23 = fmaf(x2, w.w, a23);
        a30 = fmaf(x3, w.x, a30); a31 = fmaf(x3, w.y, a31);
        a32 = fmaf(x3, w.z, a32); a33 = fmaf(x3, w.w, a33);
    }

    float4 asv = *(const float4*)(a_src + j0);
    float4 adv = *(const float4*)(a_dst + j0);
    int head = c >> 3;
    int wlane = (c & 7) == 0;

    #pragma unroll
    for (int rr = 0; rr < 4; ++rr) {
        float b0, b1, b2, b3;
        if (rr == 0) { b0=a00; b1=a01; b2=a02; b3=a03; }
        else if (rr == 1) { b0=a10; b1=a11; b2=a12; b3=a13; }
        else if (rr == 2) { b0=a20; b1=a21; b2=a22; b3=a23; }
        else { b0=a30; b1=a31; b2=a32; b3=a33; }
        int row = n0 + rg + rr * 8;
        bool valid = row < N;
        if (valid) {
            unsigned int lo = (unsigned int)f2bf(b0) | ((unsigned int)f2bf(b1) << 16);
            unsigned int hi = (unsigned int)f2bf(b2) | ((unsigned int)f2bf(b3) << 16);
            uint2 pk = make_uint2(lo, hi);
            *(uint2*)(Hb + (size_t)row * 128 + j0) = pk;
        }
        float ps = b0*asv.x + b1*asv.y + b2*asv.z + b3*asv.w;
        float pd = b0*adv.x + b1*adv.y + b2*adv.z + b3*adv.w;
        ps += __shfl_xor(ps, 1, 64); pd += __shfl_xor(pd, 1, 64);
        ps += __shfl_xor(ps, 2, 64); pd += __shfl_xor(pd, 2, 64);
        ps += __shfl_xor(ps, 4, 64); pd += __shfl_xor(pd, 4, 64);
        if (wlane && valid) {
            as_out[row * 4 + head] = ps;
            ad_out[row * 4 + head] = pd;
        }
    }
}

// ---------------- CSR build helpers -----------------------------------------
__global__ __launch_bounds__(256) void zero_int_kernel(int* __restrict__ p, int n)
{
    int i = blockIdx.x * 256 + threadIdx.x;
    if (i < n) p[i] = 0;
}

__global__ __launch_bounds__(256) void copy_int_kernel(
    const int* __restrict__ src, int* __restrict__ dst, int n)
{
    int i = blockIdx.x * 256 + threadIdx.x;
    if (i < n) dst[i] = src[i];
}

__global__ __launch_bounds__(256) void count_kernel(
    const int* __restrict__ edst, int E, int Et, int* __restrict__ cnt)
{
    int e = blockIdx.x * 256 + threadIdx.x;
    if (e >= Et) return;
    int d = (e < E) ? edst[e] : (e - E);
    atomicAdd(&cnt[d], 1);
}

__global__ __launch_bounds__(256) void scan_block_kernel(
    const int* __restrict__ in, int* __restrict__ out,
    int* __restrict__ bsum, int n)
{
    __shared__ int sh[256];
    int i = blockIdx.x * 256 + threadIdx.x;
    int v = (i < n) ? in[i] : 0;
    sh[threadIdx.x] = v;
    __syncthreads();
    #pragma unroll
    for (int off = 1; off < 256; off <<= 1) {
        int t = 0;
        if (threadIdx.x >= off) t = sh[threadIdx.x - off];
        __syncthreads();
        if (threadIdx.x >= off) sh[threadIdx.x] += t;
        __syncthreads();
    }
    if (i < n) out[i] = sh[threadIdx.x] - v;
    if (threadIdx.x == 255) bsum[blockIdx.x] = sh[255];
}

__global__ __launch_bounds__(256) void scan_add_kernel(
    int* __restrict__ offs, const int* __restrict__ bsum, int n)
{
    int i = blockIdx.x * 256 + threadIdx.x;
    if (i < n) offs[i] += bsum[blockIdx.x];
}

__global__ __launch_bounds__(256) void fill_kernel(
    const int* __restrict__ esrc, const int* __restrict__ edst, int E, int Et,
    int* __restrict__ cur, int* __restrict__ csr)
{
    int e = blockIdx.x * 256 + threadIdx.x;
    if (e >= Et) return;
    int s, d;
    if (e < E) { s = esrc[e]; d = edst[e]; } else { s = d = e - E; }
    int pos = atomicAdd(&cur[d], 1);
    csr[pos] = s;
}

// ---------------- fused softmax + gather + bias + relu ----------------------
// one wave per destination node, 4 waves/block. Per 64-edge chunk:
//   each lane owns one edge: load src idx + as[src], compute leaky e, chunk
//   max/sum via 64-lane shuffle trees, online-rescale acc, park
//   {w0,w2,w1,w3} and src in this wave's LDS slice; then feature loop reads
//   them back broadcast (ds_read_b64/b32) and gathers bf16 H rows.
__global__ __launch_bounds__(256) void gat_fused_kernel(
    const unsigned short* __restrict__ Hb, const int* __restrict__ csr,
    const int* __restrict__ offs, const int* __restrict__ cnt,
    const float* __restrict__ as, const float* __restrict__ ad,
    const float* __restrict__ bias, float* __restrict__ out, int N)
{
    __shared__ float wtab[4 * 64 * 4];   // per wave: 64 edges x {w0,w2,w1,w3}
    __shared__ int   stab[4 * 64];

    int wv = threadIdx.x >> 6;
    int d = blockIdx.x * 4 + wv;
    if (d >= N) return;
    int lane = threadIdx.x & 63;
    int start = offs[d];
    int deg = cnt[d];
    float4 adv = *(const float4*)(ad + d * 4);
    int hsel = lane >> 5;

    float m0 = -INFINITY, m1 = -INFINITY, m2 = -INFINITY, m3 = -INFINITY;
    float s0 = 0.f, s1 = 0.f, s2 = 0.f, s3 = 0.f;
    float acc0 = 0.f, acc1 = 0.f;

    for (int c0 = 0; c0 < deg; c0 += 64) {
        int rem = deg - c0;
        int len = rem < 64 ? rem : 64;
        bool valid = lane < len;
        int sidx = valid ? csr[start + c0 + lane] : 0;
        float4 av = *(const float4*)(as + sidx * 4);
        float e0 = av.x + adv.x; e0 = e0 > 0.f ? e0 : NEG_SLOPE * e0;
        float e1 = av.y + adv.y; e1 = e1 > 0.f ? e1 : NEG_SLOPE * e1;
        float e2 = av.z + adv.z; e2 = e2 > 0.f ? e2 : NEG_SLOPE * e2;
        float e3 = av.w + adv.w; e3 = e3 > 0.f ? e3 : NEG_SLOPE * e3;
        if (!valid) { e0 = e1 = e2 = e3 = -INFINITY; }

        float c0m = e0, c1m = e1, c2m = e2, c3m = e3;
        #pragma unroll
        for (int off = 32; off; off >>= 1) {
            c0m = fmaxf(c0m, __shfl_xor(c0m, off, 64));
            c1m = fmaxf(c1m, __shfl_xor(c1m, off, 64));
            c2m = fmaxf(c2m, __shfl_xor(c2m, off, 64));
            c3m = fmaxf(c3m, __shfl_xor(c3m, off, 64));
        }
        float nm0 = fmaxf(m0, c0m), nm1 = fmaxf(m1, c1m);
        float nm2 = fmaxf(m2, c2m), nm3 = fmaxf(m3, c3m);
        float r0 = __expf(m0 - nm0), r1 = __expf(m1 - nm1);
        float r2 = __expf(m2 - nm2), r3 = __expf(m3 - nm3);
        m0 = nm0; m1 = nm1; m2 = nm2; m3 = nm3;

        float w0 = valid ? __expf(e0 - m0) : 0.f;
        float w1 = valid ? __expf(e1 - m1) : 0.f;
        float w2 = valid ? __expf(e2 - m2) : 0.f;
        float w3 = valid ? __expf(e3 - m3) : 0.f;

        float t0 = w0, t1 = w1, t2 = w2, t3 = w3;
        #pragma unroll
        for (int off = 32; off; off >>= 1) {
            t0 += __shfl_xor(t0, off, 64);
            t1 += __shfl_xor(t1, off, 64);
            t2 += __shfl_xor(t2, off, 64);
            t3 += __shfl_xor(t3, off, 64);
        }
        s0 = s0 * r0 + t0; s1 = s1 * r1 + t1;
        s2 = s2 * r2 + t2; s3 = s3 * r3 + t3;
        acc0 *= hsel ? r1 : r0;
        acc1 *= hsel ? r3 : r2;

        ((float4*)wtab)[threadIdx.x] = make_float4(w0, w2, w1, w3);
        stab[threadIdx.x] = sidx;

        const float* wbase = wtab + (wv * 64) * 4 + hsel * 2;
        const int*   sbase = stab + wv * 64;
        #pragma unroll 2
        for (int kk = 0; kk < len; ++kk) {
            int sk = sbase[kk];
            float2 wp = *(const float2*)(wbase + kk * 4);
            const unsigned short* hr = Hb + (size_t)sk * 128;
            acc0 = fmaf(wp.x, bf2f(hr[lane]),      acc0);
            acc1 = fmaf(wp.y, bf2f(hr[lane + 64]), acc1);
        }
    }

    float ilo = 1.f / ((hsel ? s1 : s0) + 1e-16f);
    float ihi = 1.f / ((hsel ? s3 : s2) + 1e-16f);
    float o0 = acc0 * ilo + bias[lane];
    float o1 = acc1 * ihi + bias[lane + 64];
    out[(size_t)d * 128 + lane]      = fmaxf(o0, 0.f);
    out[(size_t)d * 128 + lane + 64] = fmaxf(o1, 0.f);
}

// ---------------- classifier head -------------------------------------------
__global__ __launch_bounds__(256) void classifier_kernel(
    const float* __restrict__ X, const float* __restrict__ Wc1,
    const float* __restrict__ bc1, const float* __restrict__ Wc2,
    const float* __restrict__ bc2, float* __restrict__ out, int N)
{
    int n = blockIdx.x * 8 + (threadIdx.x >> 5);
    if (n >= N) return;
    int j = threadIdx.x & 31;
    const float* xrow = X + (size_t)n * 128;
    float acc = bc1[j];
    #pragma unroll 8
    for (int k = 0; k < 128; ++k)
        acc = fmaf(xrow[k], Wc1[k * 32 + j], acc);
    float y = acc * Wc2[j];
    #pragma unroll
    for (int off = 16; off; off >>= 1) y += __shfl_xor(y, off, 64);
    if (j == 0)
        out[n] = 1.0f / (1.0f + expf(-(y + bc2[0])));
}

extern "C" void kernel_launch(void* const* d_in, const int* in_sizes, int n_in,
                              void* d_out, int out_size, void* d_ws, size_t ws_size,
                              hipStream_t stream)
{
    const float* x      = (const float*)d_in[0];
    const int*   eidx   = (const int*)d_in[1];
    const float* W1     = (const float*)d_in[2];
    const float* a_src1 = (const float*)d_in[3];
    const float* a_dst1 = (const float*)d_in[4];
    const float* b1     = (const float*)d_in[5];
    const float* W2     = (const float*)d_in[6];
    const float* a_src2 = (const float*)d_in[7];
    const float* a_dst2 = (const float*)d_in[8];
    const float* b2     = (const float*)d_in[9];
    const float* Wc1    = (const float*)d_in[10];
    const float* bc1    = (const float*)d_in[11];
    const float* Wc2    = (const float*)d_in[12];
    const float* bc2    = (const float*)d_in[13];

    int N  = in_sizes[0] / 128;
    int E  = in_sizes[1] / 2;
    int Et = E + N;
    const int* esrc = eidx;
    const int* edst = eidx + E;

    char* wsb = (char*)d_ws;
    unsigned short* Hb = (unsigned short*)wsb;  wsb += (size_t)N * 128 * 2;
    float*  f1_buf = (float*)wsb;   wsb += (size_t)N * 128 * 4;
    float*  as_buf = (float*)wsb;   wsb += (size_t)N * 4 * 4;
    float*  ad_buf = (float*)wsb;   wsb += (size_t)N * 4 * 4;
    int*    cnt    = (int*)wsb;     wsb += (size_t)N * 4;
    int*    offs   = (int*)wsb;     wsb += (size_t)N * 4;
    int*    cur    = (int*)wsb;     wsb += (size_t)N * 4;
    int*    bsum   = (int*)wsb;     wsb += 512 * 4;
    int*    csr    = (int*)wsb;     wsb += (size_t)Et * 4;

    int nbN = (N + 255) / 256;
    int nbE = (Et + 255) / 256;

    // ---- build CSR by destination (shared by both layers) ----
    zero_int_kernel<<<nbN, 256, 0, stream>>>(cnt, N);
    count_kernel<<<nbE, 256, 0, stream>>>(edst, E, Et, cnt);
    scan_block_kernel<<<nbN, 256, 0, stream>>>(cnt, offs, bsum, N);
    scan_block_kernel<<<1, 256, 0, stream>>>(bsum, bsum, &bsum[300], nbN);
    scan_add_kernel<<<nbN, 256, 0, stream>>>(offs, bsum, N);
    copy_int_kernel<<<nbN, 256, 0, stream>>>(offs, cur, N);
    fill_kernel<<<nbE, 256, 0, stream>>>(esrc, edst, E, Et, cur, csr);

    // ---- layer 1: x -> f1 ----
    gemm_alpha_kernel<<<(N + 31) / 32, 256, 0, stream>>>(x, W1, a_src1, a_dst1,
                                                         Hb, as_buf, ad_buf, N);
    gat_fused_kernel<<<(N + 3) / 4, 256, 0, stream>>>(Hb, csr, offs, cnt,
                                                      as_buf, ad_buf, b1, f1_buf, N);
    // ---- layer 2: f1 -> f1 ----
    gemm_alpha_kernel<<<(N + 31) / 32, 256, 0, stream>>>(f1_buf, W2, a_src2, a_dst2,
                                                         Hb, as_buf, ad_buf, N);
    gat_fused_kernel<<<(N + 3) / 4, 256, 0, stream>>>(Hb, csr, offs, cnt,
                                                      as_buf, ad_buf, b2, f1_buf, N);

    // ---- classifier head -> d_out [N] ----
    classifier_kernel<<<(N + 7) / 8, 256, 0, stream>>>(f1_buf, Wc1, bc1, Wc2, bc2,
                                                       (float*)d_out, N);
}

// Round 8
// 398.685 us; speedup vs baseline: 2.3111x; 1.0052x over previous
//
#include <hip/hip_runtime.h>
#include <hip/hip_bf16.h>
#include <math.h>

#define NEG_SLOPE 0.2f

__device__ __forceinline__ unsigned short f2bf(float f) {
    unsigned int u = __float_as_uint(f);
    u = (u + 0x7fffu + ((u >> 16) & 1u)) >> 16;      // round-to-nearest-even
    return (unsigned short)u;
}
__device__ __forceinline__ float bf2f(unsigned short u) {
    return __uint_as_float((unsigned int)u << 16);
}
__device__ __forceinline__ float bflo(unsigned int p) {
    return __uint_as_float(p << 16);
}
__device__ __forceinline__ float bfhi(unsigned int p) {
    return __uint_as_float(p & 0xffff0000u);
}

// ---------------- GEMM + alpha body (shared by fused/plain kernels) ---------
// 32 rows per block, 256 threads. Thread t: row-group rg = t>>5 (rows
// rg, rg+8, rg+16, rg+24), col lane c = t&31 (cols 4c..4c+3, head c>>3).
__device__ __forceinline__ void gemm_alpha_body(
    float* __restrict__ xt,
    const float* __restrict__ X, const float* __restrict__ W,
    const float* __restrict__ a_src, const float* __restrict__ a_dst,
    unsigned short* __restrict__ Hb, float* __restrict__ as_out,
    float* __restrict__ ad_out, int N, int n0, int t)
{
    {
        const float4* src = (const float4*)(X + (size_t)n0 * 128);
        float4* dst = (float4*)xt;
        int rows = N - n0; if (rows > 32) rows = 32;
        int maxv = rows * 32;
        #pragma unroll
        for (int i = 0; i < 4; ++i) {
            int idx = t + i * 256;
            int g = idx < maxv ? idx : maxv - 1;
            dst[idx] = src[g];
        }
    }
    __syncthreads();

    int rg = t >> 5;
    int c  = t & 31;
    int j0 = c * 4;

    float a00=0.f,a01=0.f,a02=0.f,a03=0.f;
    float a10=0.f,a11=0.f,a12=0.f,a13=0.f;
    float a20=0.f,a21=0.f,a22=0.f,a23=0.f;
    float a30=0.f,a31=0.f,a32=0.f,a33=0.f;

    #pragma unroll 4
    for (int k = 0; k < 128; ++k) {
        float4 w = *(const float4*)(W + k * 128 + j0);
        float x0 = xt[(rg     ) * 128 + k];
        float x1 = xt[(rg +  8) * 128 + k];
        float x2 = xt[(rg + 16) * 128 + k];
        float x3 = xt[(rg + 24) * 128 + k];
        a00 = fmaf(x0, w.x, a00); a01 = fmaf(x0, w.y, a01);
        a02 = fmaf(x0, w.z, a02); a03 = fmaf(x0, w.w, a03);
        a10 = fmaf(x1, w.x, a10); a11 = fmaf(x1, w.y, a11);
        a12 = fmaf(x1, w.z, a12); a13 = fmaf(x1, w.w, a13);
        a20 = fmaf(x2, w.x, a20); a21 = fmaf(x2, w.y, a21);
        a22 = fmaf(x2, w.z, a22); a23 = fmaf(x2, w.w, a23);
        a30 = fmaf(x3, w.x, a30); a31 = fmaf(x3, w.y, a31);
        a32 = fmaf(x3, w.z, a32); a33 = fmaf(x3, w.w, a33);
    }

    float4 asv = *(const float4*)(a_src + j0);
    float4 adv = *(const float4*)(a_dst + j0);
    int head = c >> 3;
    int wlane = (c & 7) == 0;

    #pragma unroll
    for (int rr = 0; rr < 4; ++rr) {
        float b0, b1, b2, b3;
        if (rr == 0) { b0=a00; b1=a01; b2=a02; b3=a03; }
        else if (rr == 1) { b0=a10; b1=a11; b2=a12; b3=a13; }
        else if (rr == 2) { b0=a20; b1=a21; b2=a22; b3=a23; }
        else { b0=a30; b1=a31; b2=a32; b3=a33; }
        int row = n0 + rg + rr * 8;
        bool valid = row < N;
        if (valid) {
            unsigned int lo = (unsigned int)f2bf(b0) | ((unsigned int)f2bf(b1) << 16);
            unsigned int hi = (unsigned int)f2bf(b2) | ((unsigned int)f2bf(b3) << 16);
            *(uint2*)(Hb + (size_t)row * 128 + j0) = make_uint2(lo, hi);
        }
        float ps = b0*asv.x + b1*asv.y + b2*asv.z + b3*asv.w;
        float pd = b0*adv.x + b1*adv.y + b2*adv.z + b3*adv.w;
        ps += __shfl_xor(ps, 1, 64); pd += __shfl_xor(pd, 1, 64);
        ps += __shfl_xor(ps, 2, 64); pd += __shfl_xor(pd, 2, 64);
        ps += __shfl_xor(ps, 4, 64); pd += __shfl_xor(pd, 4, 64);
        if (wlane && valid) {
            as_out[row * 4 + head] = ps;
            ad_out[row * 4 + head] = pd;
        }
    }
}

__global__ __launch_bounds__(256) void gemm_alpha_kernel(
    const float* __restrict__ X, const float* __restrict__ W,
    const float* __restrict__ a_src, const float* __restrict__ a_dst,
    unsigned short* __restrict__ Hb, float* __restrict__ as_out,
    float* __restrict__ ad_out, int N)
{
    __shared__ float xt[32 * 128];
    gemm_alpha_body(xt, X, W, a_src, a_dst, Hb, as_out, ad_out, N,
                    blockIdx.x * 32, threadIdx.x);
}

// ---- layer-1 GEMM fused with CSR fill (independent work, complementary pipes)
__global__ __launch_bounds__(256) void gemm_fill_kernel(
    const float* __restrict__ X, const float* __restrict__ W,
    const float* __restrict__ a_src, const float* __restrict__ a_dst,
    unsigned short* __restrict__ Hb, float* __restrict__ as_out,
    float* __restrict__ ad_out, int N,
    const int* __restrict__ esrc, const int* __restrict__ edst, int E, int Et,
    int* __restrict__ cur, int* __restrict__ csr, int gemmBlocks)
{
    __shared__ float xt[32 * 128];
    if (blockIdx.x < gemmBlocks) {
        gemm_alpha_body(xt, X, W, a_src, a_dst, Hb, as_out, ad_out, N,
                        blockIdx.x * 32, threadIdx.x);
    } else {
        int e = (blockIdx.x - gemmBlocks) * 256 + threadIdx.x;
        if (e >= Et) return;
        int s, d;
        if (e < E) { s = esrc[e]; d = edst[e]; } else { s = d = e - E; }
        int pos = atomicAdd(&cur[d], 1);
        csr[pos] = s;
    }
}

// ---------------- CSR build helpers -----------------------------------------
__global__ __launch_bounds__(256) void zero_int_kernel(int* __restrict__ p, int n)
{
    int i = blockIdx.x * 256 + threadIdx.x;
    if (i < n) p[i] = 0;
}

__global__ __launch_bounds__(256) void count_kernel(
    const int* __restrict__ edst, int E, int Et, int* __restrict__ cnt)
{
    int e = blockIdx.x * 256 + threadIdx.x;
    if (e >= Et) return;
    int d = (e < E) ? edst[e] : (e - E);
    atomicAdd(&cnt[d], 1);
}

__global__ __launch_bounds__(256) void scan_block_kernel(
    const int* __restrict__ in, int* __restrict__ out,
    int* __restrict__ bsum, int n)
{
    __shared__ int sh[256];
    int i = blockIdx.x * 256 + threadIdx.x;
    int v = (i < n) ? in[i] : 0;
    sh[threadIdx.x] = v;
    __syncthreads();
    #pragma unroll
    for (int off = 1; off < 256; off <<= 1) {
        int t = 0;
        if (threadIdx.x >= off) t = sh[threadIdx.x - off];
        __syncthreads();
        if (threadIdx.x >= off) sh[threadIdx.x] += t;
        __syncthreads();
    }
    if (i < n) out[i] = sh[threadIdx.x] - v;
    if (threadIdx.x == 255) bsum[blockIdx.x] = sh[255];
}

// offs[i] += bsum[block]; cur[i] = offs[i]  (fused add+copy)
__global__ __launch_bounds__(256) void scan_add_copy_kernel(
    int* __restrict__ offs, const int* __restrict__ bsum,
    int* __restrict__ cur, int n)
{
    int i = blockIdx.x * 256 + threadIdx.x;
    if (i < n) {
        int v = offs[i] + bsum[blockIdx.x];
        offs[i] = v;
        cur[i] = v;
    }
}

// ---------------- fused softmax + gather + bias + relu ----------------------
// one wave per destination node, 4 waves/block. Lane l owns features
// {2l, 2l+1} (same head h = l>>4). Softmax chunk phase: lane owns one edge,
// 64-lane shuffle max/sum with online rescale; weights parked in LDS
// {w0,w1,w2,w3}; feature loop 4x-unrolled with 4 independent packed-uint
// gathers in flight per lane.
__global__ __launch_bounds__(256) void gat_fused_kernel(
    const unsigned short* __restrict__ Hb, const int* __restrict__ csr,
    const int* __restrict__ offs, const int* __restrict__ cnt,
    const float* __restrict__ as, const float* __restrict__ ad,
    const float* __restrict__ bias, float* __restrict__ out, int N)
{
    __shared__ float wtab[4 * 64 * 4];   // per wave: 64 edges x {w0,w1,w2,w3}
    __shared__ int   stab[4 * 64];

    int wv = threadIdx.x >> 6;
    int d = blockIdx.x * 4 + wv;
    if (d >= N) return;
    int lane = threadIdx.x & 63;
    int start = offs[d];
    int deg = cnt[d];
    float4 adv = *(const float4*)(ad + d * 4);
    int h = lane >> 4;                 // head for features 2l, 2l+1
    int f0 = lane * 2;

    float m0 = -INFINITY, m1 = -INFINITY, m2 = -INFINITY, m3 = -INFINITY;
    float s0 = 0.f, s1 = 0.f, s2 = 0.f, s3 = 0.f;
    float acc0 = 0.f, acc1 = 0.f;

    const float* wbase = wtab + (wv * 64) * 4 + h;
    const int*   sbase = stab + wv * 64;

    for (int c0 = 0; c0 < deg; c0 += 64) {
        int rem = deg - c0;
        int len = rem < 64 ? rem : 64;
        bool valid = lane < len;
        int sidx = valid ? csr[start + c0 + lane] : 0;
        float4 av = *(const float4*)(as + sidx * 4);
        float e0 = av.x + adv.x; e0 = e0 > 0.f ? e0 : NEG_SLOPE * e0;
        float e1 = av.y + adv.y; e1 = e1 > 0.f ? e1 : NEG_SLOPE * e1;
        float e2 = av.z + adv.z; e2 = e2 > 0.f ? e2 : NEG_SLOPE * e2;
        float e3 = av.w + adv.w; e3 = e3 > 0.f ? e3 : NEG_SLOPE * e3;
        if (!valid) { e0 = e1 = e2 = e3 = -INFINITY; }

        float c0m = e0, c1m = e1, c2m = e2, c3m = e3;
        #pragma unroll
        for (int off = 32; off; off >>= 1) {
            c0m = fmaxf(c0m, __shfl_xor(c0m, off, 64));
            c1m = fmaxf(c1m, __shfl_xor(c1m, off, 64));
            c2m = fmaxf(c2m, __shfl_xor(c2m, off, 64));
            c3m = fmaxf(c3m, __shfl_xor(c3m, off, 64));
        }
        float nm0 = fmaxf(m0, c0m), nm1 = fmaxf(m1, c1m);
        float nm2 = fmaxf(m2, c2m), nm3 = fmaxf(m3, c3m);
        float r0 = __expf(m0 - nm0), r1 = __expf(m1 - nm1);
        float r2 = __expf(m2 - nm2), r3 = __expf(m3 - nm3);
        m0 = nm0; m1 = nm1; m2 = nm2; m3 = nm3;

        float w0 = valid ? __expf(e0 - m0) : 0.f;
        float w1 = valid ? __expf(e1 - m1) : 0.f;
        float w2 = valid ? __expf(e2 - m2) : 0.f;
        float w3 = valid ? __expf(e3 - m3) : 0.f;

        float t0 = w0, t1 = w1, t2 = w2, t3 = w3;
        #pragma unroll
        for (int off = 32; off; off >>= 1) {
            t0 += __shfl_xor(t0, off, 64);
            t1 += __shfl_xor(t1, off, 64);
            t2 += __shfl_xor(t2, off, 64);
            t3 += __shfl_xor(t3, off, 64);
        }
        s0 = s0 * r0 + t0; s1 = s1 * r1 + t1;
        s2 = s2 * r2 + t2; s3 = s3 * r3 + t3;
        float rs = h == 0 ? r0 : (h == 1 ? r1 : (h == 2 ? r2 : r3));
        acc0 *= rs;
        acc1 *= rs;

        ((float4*)wtab)[threadIdx.x] = make_float4(w0, w1, w2, w3);
        stab[threadIdx.x] = sidx;

        int kk = 0;
        for (; kk + 4 <= len; kk += 4) {
            int sk0 = sbase[kk+0], sk1 = sbase[kk+1];
            int sk2 = sbase[kk+2], sk3 = sbase[kk+3];
            float wa = wbase[(kk+0)*4], wb = wbase[(kk+1)*4];
            float wc = wbase[(kk+2)*4], wd = wbase[(kk+3)*4];
            unsigned int p0 = *(const unsigned int*)(Hb + (size_t)sk0 * 128 + f0);
            unsigned int p1 = *(const unsigned int*)(Hb + (size_t)sk1 * 128 + f0);
            unsigned int p2 = *(const unsigned int*)(Hb + (size_t)sk2 * 128 + f0);
            unsigned int p3 = *(const unsigned int*)(Hb + (size_t)sk3 * 128 + f0);
            acc0 = fmaf(wa, bflo(p0), acc0); acc1 = fmaf(wa, bfhi(p0), acc1);
            acc0 = fmaf(wb, bflo(p1), acc0); acc1 = fmaf(wb, bfhi(p1), acc1);
            acc0 = fmaf(wc, bflo(p2), acc0); acc1 = fmaf(wc, bfhi(p2), acc1);
            acc0 = fmaf(wd, bflo(p3), acc0); acc1 = fmaf(wd, bfhi(p3), acc1);
        }
        for (; kk < len; ++kk) {
            int sk = sbase[kk];
            float wk = wbase[kk*4];
            unsigned int p = *(const unsigned int*)(Hb + (size_t)sk * 128 + f0);
            acc0 = fmaf(wk, bflo(p), acc0);
            acc1 = fmaf(wk, bfhi(p), acc1);
        }
    }

    float sh = h == 0 ? s0 : (h == 1 ? s1 : (h == 2 ? s2 : s3));
    float inv = 1.f / (sh + 1e-16f);
    float2 bv = *(const float2*)(bias + f0);
    float o0 = acc0 * inv + bv.x;
    float o1 = acc1 * inv + bv.y;
    *(float2*)(out + (size_t)d * 128 + f0) = make_float2(fmaxf(o0, 0.f), fmaxf(o1, 0.f));
}

// ---------------- classifier head -------------------------------------------
__global__ __launch_bounds__(256) void classifier_kernel(
    const float* __restrict__ X, const float* __restrict__ Wc1,
    const float* __restrict__ bc1, const float* __restrict__ Wc2,
    const float* __restrict__ bc2, float* __restrict__ out, int N)
{
    int n = blockIdx.x * 8 + (threadIdx.x >> 5);
    if (n >= N) return;
    int j = threadIdx.x & 31;
    const float* xrow = X + (size_t)n * 128;
    float acc = bc1[j];
    #pragma unroll 8
    for (int k = 0; k < 128; ++k)
        acc = fmaf(xrow[k], Wc1[k * 32 + j], acc);
    float y = acc * Wc2[j];
    #pragma unroll
    for (int off = 16; off; off >>= 1) y += __shfl_xor(y, off, 64);
    if (j == 0)
        out[n] = 1.0f / (1.0f + expf(-(y + bc2[0])));
}

extern "C" void kernel_launch(void* const* d_in, const int* in_sizes, int n_in,
                              void* d_out, int out_size, void* d_ws, size_t ws_size,
                              hipStream_t stream)
{
    const float* x      = (const float*)d_in[0];
    const int*   eidx   = (const int*)d_in[1];
    const float* W1     = (const float*)d_in[2];
    const float* a_src1 = (const float*)d_in[3];
    const float* a_dst1 = (const float*)d_in[4];
    const float* b1     = (const float*)d_in[5];
    const float* W2     = (const float*)d_in[6];
    const float* a_src2 = (const float*)d_in[7];
    const float* a_dst2 = (const float*)d_in[8];
    const float* b2     = (const float*)d_in[9];
    const float* Wc1    = (const float*)d_in[10];
    const float* bc1    = (const float*)d_in[11];
    const float* Wc2    = (const float*)d_in[12];
    const float* bc2    = (const float*)d_in[13];

    int N  = in_sizes[0] / 128;
    int E  = in_sizes[1] / 2;
    int Et = E + N;
    const int* esrc = eidx;
    const int* edst = eidx + E;

    char* wsb = (char*)d_ws;
    unsigned short* Hb = (unsigned short*)wsb;  wsb += (size_t)N * 128 * 2;
    float*  f1_buf = (float*)wsb;   wsb += (size_t)N * 128 * 4;
    float*  as_buf = (float*)wsb;   wsb += (size_t)N * 4 * 4;
    float*  ad_buf = (float*)wsb;   wsb += (size_t)N * 4 * 4;
    int*    cnt    = (int*)wsb;     wsb += (size_t)N * 4;
    int*    offs   = (int*)wsb;     wsb += (size_t)N * 4;
    int*    cur    = (int*)wsb;     wsb += (size_t)N * 4;
    int*    bsum   = (int*)wsb;     wsb += 512 * 4;
    int*    csr    = (int*)wsb;     wsb += (size_t)Et * 4;

    int nbN = (N + 255) / 256;
    int nbE = (Et + 255) / 256;
    int gemmBlocks = (N + 31) / 32;

    // ---- CSR count/scan (shared by both layers) ----
    zero_int_kernel<<<nbN, 256, 0, stream>>>(cnt, N);
    count_kernel<<<nbE, 256, 0, stream>>>(edst, E, Et, cnt);
    scan_block_kernel<<<nbN, 256, 0, stream>>>(cnt, offs, bsum, N);
    scan_block_kernel<<<1, 256, 0, stream>>>(bsum, bsum, &bsum[300], nbN);
    scan_add_copy_kernel<<<nbN, 256, 0, stream>>>(offs, bsum, cur, N);

    // ---- layer 1 GEMM fused with CSR fill (independent) ----
    gemm_fill_kernel<<<gemmBlocks + nbE, 256, 0, stream>>>(
        x, W1, a_src1, a_dst1, Hb, as_buf, ad_buf, N,
        esrc, edst, E, Et, cur, csr, gemmBlocks);
    gat_fused_kernel<<<(N + 3) / 4, 256, 0, stream>>>(Hb, csr, offs, cnt,
                                                      as_buf, ad_buf, b1, f1_buf, N);
    // ---- layer 2 ----
    gemm_alpha_kernel<<<gemmBlocks, 256, 0, stream>>>(f1_buf, W2, a_src2, a_dst2,
                                                      Hb, as_buf, ad_buf, N);
    gat_fused_kernel<<<(N + 3) / 4, 256, 0, stream>>>(Hb, csr, offs, cnt,
                                                      as_buf, ad_buf, b2, f1_buf, N);

    // ---- classifier head -> d_out [N] ----
    classifier_kernel<<<(N + 7) / 8, 256, 0, stream>>>(f1_buf, Wc1, bc1, Wc2, bc2,
                                                       (float*)d_out, N);
}

// Round 10
// 366.666 us; speedup vs baseline: 2.5129x; 1.0873x over previous
//
#include <hip/hip_runtime.h>
#include <hip/hip_bf16.h>
#include <math.h>

#define NEG_SLOPE 0.2f

__device__ __forceinline__ unsigned short f2bf(float f) {
    unsigned int u = __float_as_uint(f);
    u = (u + 0x7fffu + ((u >> 16) & 1u)) >> 16;      // round-to-nearest-even
    return (unsigned short)u;
}
__device__ __forceinline__ float bflo(unsigned int p) {
    return __uint_as_float(p << 16);
}
__device__ __forceinline__ float bfhi(unsigned int p) {
    return __uint_as_float(p & 0xffff0000u);
}

// ---------------- GEMM + alpha body ----------------------------------------
// 32 rows per block, 256 threads. Thread t: row-group rg = t>>5 (rows
// rg, rg+8, rg+16, rg+24), col lane c = t&31 (cols 4c..4c+3, head c>>3).
__device__ __forceinline__ void gemm_alpha_body(
    float* __restrict__ xt,
    const float* __restrict__ X, const float* __restrict__ W,
    const float* __restrict__ a_src, const float* __restrict__ a_dst,
    unsigned short* __restrict__ Hb, float* __restrict__ as_out,
    float* __restrict__ ad_out, int N, int n0, int t)
{
    {
        const float4* src = (const float4*)(X + (size_t)n0 * 128);
        float4* dst = (float4*)xt;
        int rows = N - n0; if (rows > 32) rows = 32;
        int maxv = rows * 32;
        #pragma unroll
        for (int i = 0; i < 4; ++i) {
            int idx = t + i * 256;
            int g = idx < maxv ? idx : maxv - 1;
            dst[idx] = src[g];
        }
    }
    __syncthreads();

    int rg = t >> 5;
    int c  = t & 31;
    int j0 = c * 4;

    float a00=0.f,a01=0.f,a02=0.f,a03=0.f;
    float a10=0.f,a11=0.f,a12=0.f,a13=0.f;
    float a20=0.f,a21=0.f,a22=0.f,a23=0.f;
    float a30=0.f,a31=0.f,a32=0.f,a33=0.f;

    #pragma unroll 4
    for (int k = 0; k < 128; ++k) {
        float4 w = *(const float4*)(W + k * 128 + j0);
        float x0 = xt[(rg     ) * 128 + k];
        float x1 = xt[(rg +  8) * 128 + k];
        float x2 = xt[(rg + 16) * 128 + k];
        float x3 = xt[(rg + 24) * 128 + k];
        a00 = fmaf(x0, w.x, a00); a01 = fmaf(x0, w.y, a01);
        a02 = fmaf(x0, w.z, a02); a03 = fmaf(x0, w.w, a03);
        a10 = fmaf(x1, w.x, a10); a11 = fmaf(x1, w.y, a11);
        a12 = fmaf(x1, w.z, a12); a13 = fmaf(x1, w.w, a13);
        a20 = fmaf(x2, w.x, a20); a21 = fmaf(x2, w.y, a21);
        a22 = fmaf(x2, w.z, a22); a23 = fmaf(x2, w.w, a23);
        a30 = fmaf(x3, w.x, a30); a31 = fmaf(x3, w.y, a31);
        a32 = fmaf(x3, w.z, a32); a33 = fmaf(x3, w.w, a33);
    }

    float4 asv = *(const float4*)(a_src + j0);
    float4 adv = *(const float4*)(a_dst + j0);
    int head = c >> 3;
    int wlane = (c & 7) == 0;

    #pragma unroll
    for (int rr = 0; rr < 4; ++rr) {
        float b0, b1, b2, b3;
        if (rr == 0) { b0=a00; b1=a01; b2=a02; b3=a03; }
        else if (rr == 1) { b0=a10; b1=a11; b2=a12; b3=a13; }
        else if (rr == 2) { b0=a20; b1=a21; b2=a22; b3=a23; }
        else { b0=a30; b1=a31; b2=a32; b3=a33; }
        int row = n0 + rg + rr * 8;
        bool valid = row < N;
        if (valid) {
            unsigned int lo = (unsigned int)f2bf(b0) | ((unsigned int)f2bf(b1) << 16);
            unsigned int hi = (unsigned int)f2bf(b2) | ((unsigned int)f2bf(b3) << 16);
            *(uint2*)(Hb + (size_t)row * 128 + j0) = make_uint2(lo, hi);
        }
        float ps = b0*asv.x + b1*asv.y + b2*asv.z + b3*asv.w;
        float pd = b0*adv.x + b1*adv.y + b2*adv.z + b3*adv.w;
        ps += __shfl_xor(ps, 1, 64); pd += __shfl_xor(pd, 1, 64);
        ps += __shfl_xor(ps, 2, 64); pd += __shfl_xor(pd, 2, 64);
        ps += __shfl_xor(ps, 4, 64); pd += __shfl_xor(pd, 4, 64);
        if (wlane && valid) {
            as_out[row * 4 + head] = ps;
            ad_out[row * 4 + head] = pd;
        }
    }
}

__global__ __launch_bounds__(256) void gemm_alpha_kernel(
    const float* __restrict__ X, const float* __restrict__ W,
    const float* __restrict__ a_src, const float* __restrict__ a_dst,
    unsigned short* __restrict__ Hb, float* __restrict__ as_out,
    float* __restrict__ ad_out, int N)
{
    __shared__ float xt[32 * 128];
    gemm_alpha_body(xt, X, W, a_src, a_dst, Hb, as_out, ad_out, N,
                    blockIdx.x * 32, threadIdx.x);
}

// ---- layer-1 GEMM interleaved with XCD-localized CSR fill ------------------
// Groups of 8 blocks alternate roles: even group -> gemm, odd group -> fill.
// Fill block: r = blockIdx&7 selects dst node-range (keeps that XCD's csr
// writes in a ~425 KB L2-resident window so lines aggregate before writeback);
// slice = group>>1 selects its portion of the edge list.
__global__ __launch_bounds__(256) void gemm_fill_kernel(
    const float* __restrict__ X, const float* __restrict__ W,
    const float* __restrict__ a_src, const float* __restrict__ a_dst,
    unsigned short* __restrict__ Hb, float* __restrict__ as_out,
    float* __restrict__ ad_out, int N,
    const int* __restrict__ esrc, const int* __restrict__ edst, int E, int Et,
    const int* __restrict__ offs, const int* __restrict__ rank,
    int* __restrict__ csr, int gemmBlocks, int NS)
{
    __shared__ float xt[32 * 128];
    int g  = blockIdx.x >> 3;
    int l8 = blockIdx.x & 7;
    if ((g & 1) == 0) {
        int gb = (g >> 1) * 8 + l8;
        if (gb < gemmBlocks)
            gemm_alpha_body(xt, X, W, a_src, a_dst, Hb, as_out, ad_out, N,
                            gb * 32, threadIdx.x);
    } else {
        int slice = g >> 1;
        if (slice >= NS) return;
        int rlo = (int)(((long long)N * l8) >> 3);
        int rhi = (int)(((long long)N * (l8 + 1)) >> 3);
        int e0 = (int)((long long)Et * slice / NS);
        int e1 = (int)((long long)Et * (slice + 1) / NS);
        for (int e = e0 + threadIdx.x; e < e1; e += 256) {
            int d = (e < E) ? edst[e] : (e - E);
            if (d >= rlo && d < rhi) {
                int s = (e < E) ? esrc[e] : d;
                csr[offs[d] + rank[e]] = s;
            }
        }
    }
}

// ---------------- CSR build helpers -----------------------------------------
__global__ __launch_bounds__(256) void zero_int_kernel(int* __restrict__ p, int n)
{
    int i = blockIdx.x * 256 + threadIdx.x;
    if (i < n) p[i] = 0;
}

// count per-dst degree AND record each edge's rank within its dst
__global__ __launch_bounds__(256) void count_rank_kernel(
    const int* __restrict__ edst, int E, int Et,
    int* __restrict__ cnt, int* __restrict__ rank)
{
    int e = blockIdx.x * 256 + threadIdx.x;
    if (e >= Et) return;
    int d = (e < E) ? edst[e] : (e - E);
    rank[e] = atomicAdd(&cnt[d], 1);
}

__global__ __launch_bounds__(256) void scan_block_kernel(
    const int* __restrict__ in, int* __restrict__ out,
    int* __restrict__ bsum, int n)
{
    __shared__ int sh[256];
    int i = blockIdx.x * 256 + threadIdx.x;
    int v = (i < n) ? in[i] : 0;
    sh[threadIdx.x] = v;
    __syncthreads();
    #pragma unroll
    for (int off = 1; off < 256; off <<= 1) {
        int t = 0;
        if (threadIdx.x >= off) t = sh[threadIdx.x - off];
        __syncthreads();
        if (threadIdx.x >= off) sh[threadIdx.x] += t;
        __syncthreads();
    }
    if (i < n) out[i] = sh[threadIdx.x] - v;
    if (threadIdx.x == 255) bsum[blockIdx.x] = sh[255];
}

__global__ __launch_bounds__(256) void scan_add_kernel(
    int* __restrict__ offs, const int* __restrict__ bsum, int n)
{
    int i = blockIdx.x * 256 + threadIdx.x;
    if (i < n) offs[i] += bsum[blockIdx.x];
}

// ---------------- fused softmax + gather + bias + relu ----------------------
// one wave per destination node, 4 waves/block. Lane l owns features
// {2l, 2l+1} (same head h = l>>4). Softmax chunk phase: lane owns one edge,
// 64-lane shuffle max/sum with online rescale; weights parked in LDS;
// feature loop 4x-unrolled with 4 independent packed-uint gathers in flight.
__global__ __launch_bounds__(256) void gat_fused_kernel(
    const unsigned short* __restrict__ Hb, const int* __restrict__ csr,
    const int* __restrict__ offs, const int* __restrict__ cnt,
    const float* __restrict__ as, const float* __restrict__ ad,
    const float* __restrict__ bias, float* __restrict__ out, int N)
{
    __shared__ float wtab[4 * 64 * 4];   // per wave: 64 edges x {w0,w1,w2,w3}
    __shared__ int   stab[4 * 64];

    int wv = threadIdx.x >> 6;
    int d = blockIdx.x * 4 + wv;
    if (d >= N) return;
    int lane = threadIdx.x & 63;
    int start = offs[d];
    int deg = cnt[d];
    float4 adv = *(const float4*)(ad + d * 4);
    int h = lane >> 4;                 // head for features 2l, 2l+1
    int f0 = lane * 2;

    float m0 = -INFINITY, m1 = -INFINITY, m2 = -INFINITY, m3 = -INFINITY;
    float s0 = 0.f, s1 = 0.f, s2 = 0.f, s3 = 0.f;
    float acc0 = 0.f, acc1 = 0.f;

    const float* wbase = wtab + (wv * 64) * 4 + h;
    const int*   sbase = stab + wv * 64;

    for (int c0 = 0; c0 < deg; c0 += 64) {
        int rem = deg - c0;
        int len = rem < 64 ? rem : 64;
        bool valid = lane < len;
        int sidx = valid ? csr[start + c0 + lane] : 0;
        float4 av = *(const float4*)(as + sidx * 4);
        float e0 = av.x + adv.x; e0 = e0 > 0.f ? e0 : NEG_SLOPE * e0;
        float e1 = av.y + adv.y; e1 = e1 > 0.f ? e1 : NEG_SLOPE * e1;
        float e2 = av.z + adv.z; e2 = e2 > 0.f ? e2 : NEG_SLOPE * e2;
        float e3 = av.w + adv.w; e3 = e3 > 0.f ? e3 : NEG_SLOPE * e3;
        if (!valid) { e0 = e1 = e2 = e3 = -INFINITY; }

        float c0m = e0, c1m = e1, c2m = e2, c3m = e3;
        #pragma unroll
        for (int off = 32; off; off >>= 1) {
            c0m = fmaxf(c0m, __shfl_xor(c0m, off, 64));
            c1m = fmaxf(c1m, __shfl_xor(c1m, off, 64));
            c2m = fmaxf(c2m, __shfl_xor(c2m, off, 64));
            c3m = fmaxf(c3m, __shfl_xor(c3m, off, 64));
        }
        float nm0 = fmaxf(m0, c0m), nm1 = fmaxf(m1, c1m);
        float nm2 = fmaxf(m2, c2m), nm3 = fmaxf(m3, c3m);
        float r0 = __expf(m0 - nm0), r1 = __expf(m1 - nm1);
        float r2 = __expf(m2 - nm2), r3 = __expf(m3 - nm3);
        m0 = nm0; m1 = nm1; m2 = nm2; m3 = nm3;

        float w0 = valid ? __expf(e0 - m0) : 0.f;
        float w1 = valid ? __expf(e1 - m1) : 0.f;
        float w2 = valid ? __expf(e2 - m2) : 0.f;
        float w3 = valid ? __expf(e3 - m3) : 0.f;

        float t0 = w0, t1 = w1, t2 = w2, t3 = w3;
        #pragma unroll
        for (int off = 32; off; off >>= 1) {
            t0 += __shfl_xor(t0, off, 64);
            t1 += __shfl_xor(t1, off, 64);
            t2 += __shfl_xor(t2, off, 64);
            t3 += __shfl_xor(t3, off, 64);
        }
        s0 = s0 * r0 + t0; s1 = s1 * r1 + t1;
        s2 = s2 * r2 + t2; s3 = s3 * r3 + t3;
        float rs = h == 0 ? r0 : (h == 1 ? r1 : (h == 2 ? r2 : r3));
        acc0 *= rs;
        acc1 *= rs;

        ((float4*)wtab)[threadIdx.x] = make_float4(w0, w1, w2, w3);
        stab[threadIdx.x] = sidx;

        int kk = 0;
        for (; kk + 4 <= len; kk += 4) {
            int sk0 = sbase[kk+0], sk1 = sbase[kk+1];
            int sk2 = sbase[kk+2], sk3 = sbase[kk+3];
            float wa = wbase[(kk+0)*4], wb = wbase[(kk+1)*4];
            float wc = wbase[(kk+2)*4], wd = wbase[(kk+3)*4];
            unsigned int p0 = *(const unsigned int*)(Hb + (size_t)sk0 * 128 + f0);
            unsigned int p1 = *(const unsigned int*)(Hb + (size_t)sk1 * 128 + f0);
            unsigned int p2 = *(const unsigned int*)(Hb + (size_t)sk2 * 128 + f0);
            unsigned int p3 = *(const unsigned int*)(Hb + (size_t)sk3 * 128 + f0);
            acc0 = fmaf(wa, bflo(p0), acc0); acc1 = fmaf(wa, bfhi(p0), acc1);
            acc0 = fmaf(wb, bflo(p1), acc0); acc1 = fmaf(wb, bfhi(p1), acc1);
            acc0 = fmaf(wc, bflo(p2), acc0); acc1 = fmaf(wc, bfhi(p2), acc1);
            acc0 = fmaf(wd, bflo(p3), acc0); acc1 = fmaf(wd, bfhi(p3), acc1);
        }
        for (; kk < len; ++kk) {
            int sk = sbase[kk];
            float wk = wbase[kk*4];
            unsigned int p = *(const unsigned int*)(Hb + (size_t)sk * 128 + f0);
            acc0 = fmaf(wk, bflo(p), acc0);
            acc1 = fmaf(wk, bfhi(p), acc1);
        }
    }

    float sh = h == 0 ? s0 : (h == 1 ? s1 : (h == 2 ? s2 : s3));
    float inv = 1.f / (sh + 1e-16f);
    float2 bv = *(const float2*)(bias + f0);
    float o0 = acc0 * inv + bv.x;
    float o1 = acc1 * inv + bv.y;
    *(float2*)(out + (size_t)d * 128 + f0) = make_float2(fmaxf(o0, 0.f), fmaxf(o1, 0.f));
}

// ---------------- classifier head -------------------------------------------
__global__ __launch_bounds__(256) void classifier_kernel(
    const float* __restrict__ X, const float* __restrict__ Wc1,
    const float* __restrict__ bc1, const float* __restrict__ Wc2,
    const float* __restrict__ bc2, float* __restrict__ out, int N)
{
    int n = blockIdx.x * 8 + (threadIdx.x >> 5);
    if (n >= N) return;
    int j = threadIdx.x & 31;
    const float* xrow = X + (size_t)n * 128;
    float acc = bc1[j];
    #pragma unroll 8
    for (int k = 0; k < 128; ++k)
        acc = fmaf(xrow[k], Wc1[k * 32 + j], acc);
    float y = acc * Wc2[j];
    #pragma unroll
    for (int off = 16; off; off >>= 1) y += __shfl_xor(y, off, 64);
    if (j == 0)
        out[n] = 1.0f / (1.0f + expf(-(y + bc2[0])));
}

extern "C" void kernel_launch(void* const* d_in, const int* in_sizes, int n_in,
                              void* d_out, int out_size, void* d_ws, size_t ws_size,
                              hipStream_t stream)
{
    const float* x      = (const float*)d_in[0];
    const int*   eidx   = (const int*)d_in[1];
    const float* W1     = (const float*)d_in[2];
    const float* a_src1 = (const float*)d_in[3];
    const float* a_dst1 = (const float*)d_in[4];
    const float* b1     = (const float*)d_in[5];
    const float* W2     = (const float*)d_in[6];
    const float* a_src2 = (const float*)d_in[7];
    const float* a_dst2 = (const float*)d_in[8];
    const float* b2     = (const float*)d_in[9];
    const float* Wc1    = (const float*)d_in[10];
    const float* bc1    = (const float*)d_in[11];
    const float* Wc2    = (const float*)d_in[12];
    const float* bc2    = (const float*)d_in[13];

    int N  = in_sizes[0] / 128;
    int E  = in_sizes[1] / 2;
    int Et = E + N;
    const int* esrc = eidx;
    const int* edst = eidx + E;

    char* wsb = (char*)d_ws;
    unsigned short* Hb = (unsigned short*)wsb;  wsb += (size_t)N * 128 * 2;
    float*  f1_buf = (float*)wsb;   wsb += (size_t)N * 128 * 4;
    float*  as_buf = (float*)wsb;   wsb += (size_t)N * 4 * 4;
    float*  ad_buf = (float*)wsb;   wsb += (size_t)N * 4 * 4;
    int*    cnt    = (int*)wsb;     wsb += (size_t)N * 4;
    int*    offs   = (int*)wsb;     wsb += (size_t)N * 4;
    int*    bsum   = (int*)wsb;     wsb += 512 * 4;
    int*    csr    = (int*)wsb;     wsb += (size_t)Et * 4;
    int*    rank   = (int*)wsb;     wsb += (size_t)Et * 4;

    int nbN = (N + 255) / 256;
    int nbE = (Et + 255) / 256;
    int gemmBlocks = (N + 31) / 32;
    int gemmGroups = (gemmBlocks + 7) / 8;
    int NS = gemmGroups;                       // fill slices (one odd group each)
    int fusedGrid = gemmGroups * 2 * 8;

    // ---- CSR count/scan (shared by both layers) ----
    zero_int_kernel<<<nbN, 256, 0, stream>>>(cnt, N);
    count_rank_kernel<<<nbE, 256, 0, stream>>>(edst, E, Et, cnt, rank);
    scan_block_kernel<<<nbN, 256, 0, stream>>>(cnt, offs, bsum, N);
    scan_block_kernel<<<1, 256, 0, stream>>>(bsum, bsum, &bsum[300], nbN);
    scan_add_kernel<<<nbN, 256, 0, stream>>>(offs, bsum, N);

    // ---- layer 1 GEMM interleaved with XCD-localized fill ----
    gemm_fill_kernel<<<fusedGrid, 256, 0, stream>>>(
        x, W1, a_src1, a_dst1, Hb, as_buf, ad_buf, N,
        esrc, edst, E, Et, offs, rank, csr, gemmBlocks, NS);
    gat_fused_kernel<<<(N + 3) / 4, 256, 0, stream>>>(Hb, csr, offs, cnt,
                                                      as_buf, ad_buf, b1, f1_buf, N);
    // ---- layer 2 ----
    gemm_alpha_kernel<<<gemmBlocks, 256, 0, stream>>>(f1_buf, W2, a_src2, a_dst2,
                                                      Hb, as_buf, ad_buf, N);
    gat_fused_kernel<<<(N + 3) / 4, 256, 0, stream>>>(Hb, csr, offs, cnt,
                                                      as_buf, ad_buf, b2, f1_buf, N);

    // ---- classifier head -> d_out [N] ----
    classifier_kernel<<<(N + 7) / 8, 256, 0, stream>>>(f1_buf, Wc1, bc1, Wc2, bc2,
                                                       (float*)d_out, N);
}